// Round 1
// baseline (2108.518 us; speedup 1.0000x reference)
//
#include <hip/hip_runtime.h>

// EdgeConv fused kernel, f32 correctness-first version.
// message m = [x_i, x_j - x_i] (64), h = ReLU(m@W1+b1) @ W2 + b2 (32),
// out[n] = max over incoming edges (dst==n), empty -> 0.

__device__ __forceinline__ unsigned int enc_f32(float f) {
    unsigned int b = __float_as_uint(f);
    // order-preserving map float -> uint; never produces 0 for real floats
    return (b & 0x80000000u) ? ~b : (b | 0x80000000u);
}

__device__ __forceinline__ float dec_f32(unsigned int u) {
    unsigned int b = (u & 0x80000000u) ? (u & 0x7FFFFFFFu) : ~u;
    return __uint_as_float(b);
}

__global__ __launch_bounds__(256) void edgeconv_edge_kernel(
    const float* __restrict__ x,
    const int* __restrict__ edge_index,   // [2, E] row-major: row0=src, row1=dst
    const float* __restrict__ W1,         // [64, 64] row-major
    const float* __restrict__ b1,         // [64]
    const float* __restrict__ W2,         // [64, 32] row-major
    const float* __restrict__ b2,         // [32]
    unsigned int* __restrict__ out,       // [N, 32] encoded-u32 max buffer
    int E)
{
    int e = blockIdx.x * blockDim.x + threadIdx.x;
    if (e >= E) return;

    int src = edge_index[e];        // j (neighbor)
    int dst = edge_index[E + e];    // i (center)

    // Build message m[0:32] = x_i, m[32:64] = x_j - x_i
    float m[64];
    const float4* xi4 = reinterpret_cast<const float4*>(x + (size_t)dst * 32);
    const float4* xj4 = reinterpret_cast<const float4*>(x + (size_t)src * 32);
#pragma unroll
    for (int q = 0; q < 8; ++q) {
        float4 a = xi4[q];
        float4 b = xj4[q];
        m[q * 4 + 0] = a.x;
        m[q * 4 + 1] = a.y;
        m[q * 4 + 2] = a.z;
        m[q * 4 + 3] = a.w;
        m[32 + q * 4 + 0] = b.x - a.x;
        m[32 + q * 4 + 1] = b.y - a.y;
        m[32 + q * 4 + 2] = b.z - a.z;
        m[32 + q * 4 + 3] = b.w - a.w;
    }

    // acc = b2 (layer-2 accumulators)
    float acc[32];
#pragma unroll
    for (int c = 0; c < 32; ++c) acc[c] = b2[c];

    // Layer 1 + fused layer 2: for each hidden unit j, h_j = ReLU(b1[j] + m.W1[:,j]),
    // then acc[c] += h_j * W2[j][c].
    for (int j = 0; j < 64; ++j) {
        float h = b1[j];
#pragma unroll
        for (int k = 0; k < 64; ++k) {
            h = fmaf(m[k], W1[k * 64 + j], h);
        }
        h = fmaxf(h, 0.0f);
#pragma unroll
        for (int c = 0; c < 32; ++c) {
            acc[c] = fmaf(h, W2[j * 32 + c], acc[c]);
        }
    }

    // Scatter-max into out[dst]
    unsigned int* o = out + (size_t)dst * 32;
#pragma unroll
    for (int c = 0; c < 32; ++c) {
        atomicMax(o + c, enc_f32(acc[c]));
    }
}

__global__ __launch_bounds__(256) void edgeconv_decode_kernel(
    unsigned int* __restrict__ buf, int n)
{
    int i = blockIdx.x * blockDim.x + threadIdx.x;
    if (i >= n) return;
    unsigned int u = buf[i];
    float f = (u == 0u) ? 0.0f : dec_f32(u);   // u==0 sentinel: node had no incoming edge
    reinterpret_cast<float*>(buf)[i] = f;
}

extern "C" void kernel_launch(void* const* d_in, const int* in_sizes, int n_in,
                              void* d_out, int out_size, void* d_ws, size_t ws_size,
                              hipStream_t stream)
{
    const float* x  = (const float*)d_in[0];
    const int*   ei = (const int*)d_in[1];
    const float* W1 = (const float*)d_in[2];
    const float* b1 = (const float*)d_in[3];
    const float* W2 = (const float*)d_in[4];
    const float* b2 = (const float*)d_in[5];

    int E = in_sizes[1] / 2;
    unsigned int* out = (unsigned int*)d_out;

    // init encoded-max buffer to sentinel 0 ("no edge seen")
    hipMemsetAsync(d_out, 0, (size_t)out_size * sizeof(float), stream);

    int threads = 256;
    int blocks_e = (E + threads - 1) / threads;
    edgeconv_edge_kernel<<<blocks_e, threads, 0, stream>>>(x, ei, W1, b1, W2, b2, out, E);

    int blocks_d = (out_size + threads - 1) / threads;
    edgeconv_decode_kernel<<<blocks_d, threads, 0, stream>>>(out, out_size);
}

// Round 2
// 825.581 us; speedup vs baseline: 2.5540x; 2.5540x over previous
//
#include <hip/hip_runtime.h>

typedef unsigned int u32;

// order-preserving float<->uint encoding; enc never returns 0 for real values
__device__ __forceinline__ u32 enc_f32(float f) {
    u32 b = __float_as_uint(f);
    return (b & 0x80000000u) ? ~b : (b | 0x80000000u);
}
__device__ __forceinline__ float dec_f32(u32 u) {
    u32 b = (u & 0x80000000u) ? (u & 0x7FFFFFFFu) : ~u;
    return __uint_as_float(b);
}

#define EPT 8            // sorted edges per thread in k_edge
#define NEG_INF __uint_as_float(0xFF800000u)

// ---------- K_prep: build WTa[j][k] = W1[k][j]-W1[k+32][j], WTb[j][k] = W1[k+32][j] ----------
__global__ __launch_bounds__(256) void k_prep(const float* __restrict__ W1,
                                              float* __restrict__ WTa, float* __restrict__ WTb) {
    for (int idx = threadIdx.x; idx < 2048; idx += 256) {
        int j = idx >> 5, k = idx & 31;
        float a = W1[k * 64 + j];
        float b = W1[(k + 32) * 64 + j];
        WTa[j * 32 + k] = a - b;
        WTb[j * 32 + k] = b;
    }
}

// ---------- K_pq: per-node tables P = x@(W1a-W1b)+b1, Q = x@W1b ----------
__global__ __launch_bounds__(256) void k_pq(const float* __restrict__ x,
                                            const float* __restrict__ WTa,
                                            const float* __restrict__ WTb,
                                            const float* __restrict__ b1,
                                            float* __restrict__ P, float* __restrict__ Q, int N) {
    int n = blockIdx.x * 256 + threadIdx.x;
    if (n >= N) return;
    float xr[32];
    const float4* x4 = reinterpret_cast<const float4*>(x + (size_t)n * 32);
#pragma unroll
    for (int q = 0; q < 8; ++q) {
        float4 v = x4[q];
        xr[4 * q] = v.x; xr[4 * q + 1] = v.y; xr[4 * q + 2] = v.z; xr[4 * q + 3] = v.w;
    }
    float4* P4 = reinterpret_cast<float4*>(P + (size_t)n * 64);
    float4* Q4 = reinterpret_cast<float4*>(Q + (size_t)n * 64);
    for (int j0 = 0; j0 < 64; j0 += 4) {
        float pv[4], qv[4];
#pragma unroll
        for (int m = 0; m < 4; ++m) {
            int j = j0 + m;
            float a = b1[j], q = 0.f;
#pragma unroll
            for (int k = 0; k < 32; ++k) {
                a = fmaf(xr[k], WTa[j * 32 + k], a);
                q = fmaf(xr[k], WTb[j * 32 + k], q);
            }
            pv[m] = a; qv[m] = q;
        }
        P4[j0 >> 2] = make_float4(pv[0], pv[1], pv[2], pv[3]);
        Q4[j0 >> 2] = make_float4(qv[0], qv[1], qv[2], qv[3]);
    }
}

// ---------- K_hist ----------
__global__ __launch_bounds__(256) void k_hist(const int* __restrict__ ei, u32* __restrict__ deg, int E) {
    int e = blockIdx.x * 256 + threadIdx.x;
    if (e >= E) return;
    atomicAdd(&deg[ei[E + e]], 1u);
}

// ---------- exclusive scan of deg -> cursor (3 kernels, 1024 items/block) ----------
__global__ __launch_bounds__(256) void k_scan1(const u32* __restrict__ deg, u32* __restrict__ cursor,
                                               u32* __restrict__ bsum, int N) {
    __shared__ u32 sh[256];
    int t = threadIdx.x;
    int base = blockIdx.x * 1024 + t * 4;
    u32 v0 = 0, v1 = 0, v2 = 0, v3 = 0;
    if (base + 3 < N) {
        uint4 vv = *reinterpret_cast<const uint4*>(deg + base);
        v0 = vv.x; v1 = vv.y; v2 = vv.z; v3 = vv.w;
    } else {
        if (base < N) v0 = deg[base];
        if (base + 1 < N) v1 = deg[base + 1];
        if (base + 2 < N) v2 = deg[base + 2];
        if (base + 3 < N) v3 = deg[base + 3];
    }
    u32 s = v0 + v1 + v2 + v3;
    sh[t] = s; __syncthreads();
    u32 acc = s;
    for (int off = 1; off < 256; off <<= 1) {
        u32 add = (t >= off) ? sh[t - off] : 0;
        __syncthreads();
        acc += add; sh[t] = acc;
        __syncthreads();
    }
    u32 excl = acc - s;
    if (base < N) cursor[base] = excl;
    if (base + 1 < N) cursor[base + 1] = excl + v0;
    if (base + 2 < N) cursor[base + 2] = excl + v0 + v1;
    if (base + 3 < N) cursor[base + 3] = excl + v0 + v1 + v2;
    if (t == 255) bsum[blockIdx.x] = acc;
}

__global__ __launch_bounds__(256) void k_scan2(const u32* __restrict__ bsum, u32* __restrict__ bsumX, int nb) {
    __shared__ u32 sh[256];
    int t = threadIdx.x;
    u32 v = (t < nb) ? bsum[t] : 0;
    sh[t] = v; __syncthreads();
    u32 acc = v;
    for (int off = 1; off < 256; off <<= 1) {
        u32 add = (t >= off) ? sh[t - off] : 0;
        __syncthreads();
        acc += add; sh[t] = acc;
        __syncthreads();
    }
    if (t < nb) bsumX[t] = acc - v;
}

__global__ __launch_bounds__(256) void k_scan3(u32* __restrict__ cursor, const u32* __restrict__ bsumX, int N) {
    int i = blockIdx.x * 256 + threadIdx.x;
    if (i >= N) return;
    cursor[i] += bsumX[i >> 10];
}

// ---------- K_scatter: bucket edges by dst (value scatter, no perm indirection later) ----------
__global__ __launch_bounds__(256) void k_scatter(const int* __restrict__ ei, u32* __restrict__ cursor,
                                                 u32* __restrict__ srcs, u32* __restrict__ dsts, int E) {
    int e = blockIdx.x * 256 + threadIdx.x;
    if (e >= E) return;
    int d = ei[E + e];
    int s = ei[e];
    u32 slot = atomicAdd(&cursor[d], 1u);
    srcs[slot] = (u32)s;
    dsts[slot] = (u32)d;
}

// ---------- K_edge: 8 sorted slots/thread, in-register run-max, boundary atomics ----------
__global__ __launch_bounds__(256) void k_edge(const float* __restrict__ P, const float* __restrict__ Q,
                                              const u32* __restrict__ srcs, const u32* __restrict__ dsts,
                                              const float* __restrict__ W2, u32* __restrict__ out, int E) {
    int t = blockIdx.x * 256 + threadIdx.x;
    int base = t * EPT;
    if (base >= E) return;
    int end = min(E, base + EPT);

    float p[64];
    float acc[32];
    int prev = -1;

    for (int slot = base; slot < end; ++slot) {
        int d = (int)dsts[slot];
        int s = (int)srcs[slot];
        if (d != prev) {
            if (prev >= 0) {
                u32* o = out + (size_t)prev * 32;
#pragma unroll
                for (int c = 0; c < 32; ++c) atomicMax(o + c, enc_f32(acc[c]));
            }
            const float4* p4 = reinterpret_cast<const float4*>(P + (size_t)d * 64);
#pragma unroll
            for (int q = 0; q < 16; ++q) {
                float4 v = p4[q];
                p[4 * q] = v.x; p[4 * q + 1] = v.y; p[4 * q + 2] = v.z; p[4 * q + 3] = v.w;
            }
#pragma unroll
            for (int c = 0; c < 32; ++c) acc[c] = NEG_INF;
            prev = d;
        }
        const float4* q4 = reinterpret_cast<const float4*>(Q + (size_t)s * 64);
        float acc2[32];
#pragma unroll
        for (int c = 0; c < 32; ++c) acc2[c] = 0.f;
#pragma unroll
        for (int jc = 0; jc < 16; ++jc) {
            float4 qv = q4[jc];
            float h0 = fmaxf(p[4 * jc + 0] + qv.x, 0.f);
            float h1 = fmaxf(p[4 * jc + 1] + qv.y, 0.f);
            float h2 = fmaxf(p[4 * jc + 2] + qv.z, 0.f);
            float h3 = fmaxf(p[4 * jc + 3] + qv.w, 0.f);
            const float* w = W2 + (size_t)(4 * jc) * 32;
#pragma unroll
            for (int c = 0; c < 32; ++c) {
                float a = acc2[c];
                a = fmaf(h0, w[c], a);
                a = fmaf(h1, w[32 + c], a);
                a = fmaf(h2, w[64 + c], a);
                a = fmaf(h3, w[96 + c], a);
                acc2[c] = a;
            }
        }
#pragma unroll
        for (int c = 0; c < 32; ++c) acc[c] = fmaxf(acc[c], acc2[c]);
    }
    if (prev >= 0) {
        u32* o = out + (size_t)prev * 32;
#pragma unroll
        for (int c = 0; c < 32; ++c) atomicMax(o + c, enc_f32(acc[c]));
    }
}

// ---------- K_decode: sentinel 0 -> 0.0 (no incoming edges), else decode + b2 ----------
__global__ __launch_bounds__(256) void k_decode(u32* __restrict__ buf, const float* __restrict__ b2, int n) {
    int i = blockIdx.x * 256 + threadIdx.x;
    if (i >= n) return;
    u32 u = buf[i];
    float f = u ? (dec_f32(u) + b2[i & 31]) : 0.f;
    reinterpret_cast<float*>(buf)[i] = f;
}

// ---------- fallback (round-1 style): monolithic edge kernel with direct atomics ----------
__global__ __launch_bounds__(256) void fb_edge(const float* __restrict__ x, const int* __restrict__ ei,
                                               const float* __restrict__ W1, const float* __restrict__ b1,
                                               const float* __restrict__ W2, const float* __restrict__ b2,
                                               u32* __restrict__ out, int E) {
    int e = blockIdx.x * 256 + threadIdx.x;
    if (e >= E) return;
    int src = ei[e], dst = ei[E + e];
    float m[64];
    const float4* xi4 = reinterpret_cast<const float4*>(x + (size_t)dst * 32);
    const float4* xj4 = reinterpret_cast<const float4*>(x + (size_t)src * 32);
#pragma unroll
    for (int q = 0; q < 8; ++q) {
        float4 a = xi4[q], b = xj4[q];
        m[q * 4] = a.x; m[q * 4 + 1] = a.y; m[q * 4 + 2] = a.z; m[q * 4 + 3] = a.w;
        m[32 + q * 4] = b.x - a.x; m[32 + q * 4 + 1] = b.y - a.y;
        m[32 + q * 4 + 2] = b.z - a.z; m[32 + q * 4 + 3] = b.w - a.w;
    }
    float acc[32];
#pragma unroll
    for (int c = 0; c < 32; ++c) acc[c] = b2[c];
    for (int j = 0; j < 64; ++j) {
        float h = b1[j];
#pragma unroll
        for (int k = 0; k < 64; ++k) h = fmaf(m[k], W1[k * 64 + j], h);
        h = fmaxf(h, 0.0f);
#pragma unroll
        for (int c = 0; c < 32; ++c) acc[c] = fmaf(h, W2[j * 32 + c], acc[c]);
    }
    u32* o = out + (size_t)dst * 32;
#pragma unroll
    for (int c = 0; c < 32; ++c) atomicMax(o + c, enc_f32(acc[c]));
}
__global__ __launch_bounds__(256) void fb_decode(u32* __restrict__ buf, int n) {
    int i = blockIdx.x * 256 + threadIdx.x;
    if (i >= n) return;
    u32 u = buf[i];
    reinterpret_cast<float*>(buf)[i] = u ? dec_f32(u) : 0.f;
}

extern "C" void kernel_launch(void* const* d_in, const int* in_sizes, int n_in,
                              void* d_out, int out_size, void* d_ws, size_t ws_size,
                              hipStream_t stream) {
    const float* x  = (const float*)d_in[0];
    const int*   ei = (const int*)d_in[1];
    const float* W1 = (const float*)d_in[2];
    const float* b1 = (const float*)d_in[3];
    const float* W2 = (const float*)d_in[4];
    const float* b2 = (const float*)d_in[5];

    int N = in_sizes[0] / 32;
    int E = in_sizes[1] / 2;
    u32* out = (u32*)d_out;

    // workspace layout (256B aligned)
    char* ws = (char*)d_ws;
    size_t off = 0;
    auto alloc = [&](size_t bytes) { char* p = ws + off; off += (bytes + 255) & ~(size_t)255; return p; };
    float* WTa   = (float*)alloc(2048 * 4);
    float* WTb   = (float*)alloc(2048 * 4);
    float* P     = (float*)alloc((size_t)N * 64 * 4);
    float* Q     = (float*)alloc((size_t)N * 64 * 4);
    u32*   deg   = (u32*)alloc((size_t)N * 4);
    u32*   cur   = (u32*)alloc((size_t)N * 4);
    u32*   bsum  = (u32*)alloc(256 * 4);
    u32*   bsumX = (u32*)alloc(256 * 4);
    u32*   srcs  = (u32*)alloc((size_t)E * 4);
    u32*   dsts  = (u32*)alloc((size_t)E * 4);
    bool fits = (off <= ws_size);

    hipMemsetAsync(d_out, 0, (size_t)out_size * 4, stream);

    if (!fits) {
        int be = (E + 255) / 256;
        fb_edge<<<be, 256, 0, stream>>>(x, ei, W1, b1, W2, b2, out, E);
        fb_decode<<<(out_size + 255) / 256, 256, 0, stream>>>(out, out_size);
        return;
    }

    hipMemsetAsync(deg, 0, (size_t)N * 4, stream);

    k_prep<<<1, 256, 0, stream>>>(W1, WTa, WTb);
    k_pq<<<(N + 255) / 256, 256, 0, stream>>>(x, WTa, WTb, b1, P, Q, N);

    int be = (E + 255) / 256;
    k_hist<<<be, 256, 0, stream>>>(ei, deg, E);

    int nb = (N + 1023) / 1024;  // 98 for N=100000, must be <= 256
    k_scan1<<<nb, 256, 0, stream>>>(deg, cur, bsum, N);
    k_scan2<<<1, 256, 0, stream>>>(bsum, bsumX, nb);
    k_scan3<<<(N + 255) / 256, 256, 0, stream>>>(cur, bsumX, N);

    k_scatter<<<be, 256, 0, stream>>>(ei, cur, srcs, dsts, E);

    int nthreads = (E + EPT - 1) / EPT;
    k_edge<<<(nthreads + 255) / 256, 256, 0, stream>>>(P, Q, srcs, dsts, W2, out, E);

    k_decode<<<(out_size + 255) / 256, 256, 0, stream>>>(out, b2, out_size);
}

// Round 3
// 423.866 us; speedup vs baseline: 4.9745x; 1.9477x over previous
//
#include <hip/hip_runtime.h>

typedef unsigned int u32;
typedef __attribute__((ext_vector_type(8))) short short8v;
typedef __attribute__((ext_vector_type(4))) float f32x4;

// order-preserving float<->uint encoding; enc never returns 0 for real values
__device__ __forceinline__ u32 enc_f32(float f) {
    u32 b = __float_as_uint(f);
    return (b & 0x80000000u) ? ~b : (b | 0x80000000u);
}
__device__ __forceinline__ float dec_f32(u32 u) {
    u32 b = (u & 0x80000000u) ? (u & 0x7FFFFFFFu) : ~u;
    return __uint_as_float(b);
}
__device__ __forceinline__ unsigned short bf16rne(float f) {
    u32 u = __float_as_uint(f);
    u32 r = (u + 0x7FFFu + ((u >> 16) & 1u)) >> 16;
    return (unsigned short)r;
}

#define NEG_INF __uint_as_float(0xFF800000u)

// ---------- K_prep: WTa[j][k] = W1[k][j]-W1[k+32][j], WTb[j][k] = W1[k+32][j] ----------
__global__ __launch_bounds__(256) void k_prep(const float* __restrict__ W1,
                                              float* __restrict__ WTa, float* __restrict__ WTb) {
    for (int idx = threadIdx.x; idx < 2048; idx += 256) {
        int j = idx >> 5, k = idx & 31;
        float a = W1[k * 64 + j];
        float b = W1[(k + 32) * 64 + j];
        WTa[j * 32 + k] = a - b;
        WTb[j * 32 + k] = b;
    }
}

// ---------- K_pq: per-node tables P = x@(W1a-W1b)+b1, Q = x@W1b ----------
__global__ __launch_bounds__(256) void k_pq(const float* __restrict__ x,
                                            const float* __restrict__ WTa,
                                            const float* __restrict__ WTb,
                                            const float* __restrict__ b1,
                                            float* __restrict__ P, float* __restrict__ Q, int N) {
    int n = blockIdx.x * 256 + threadIdx.x;
    if (n >= N) return;
    float xr[32];
    const float4* x4 = reinterpret_cast<const float4*>(x + (size_t)n * 32);
#pragma unroll
    for (int q = 0; q < 8; ++q) {
        float4 v = x4[q];
        xr[4 * q] = v.x; xr[4 * q + 1] = v.y; xr[4 * q + 2] = v.z; xr[4 * q + 3] = v.w;
    }
    float4* P4 = reinterpret_cast<float4*>(P + (size_t)n * 64);
    float4* Q4 = reinterpret_cast<float4*>(Q + (size_t)n * 64);
    for (int j0 = 0; j0 < 64; j0 += 4) {
        float pv[4], qv[4];
#pragma unroll
        for (int m = 0; m < 4; ++m) {
            int j = j0 + m;
            float a = b1[j], q = 0.f;
#pragma unroll
            for (int k = 0; k < 32; ++k) {
                a = fmaf(xr[k], WTa[j * 32 + k], a);
                q = fmaf(xr[k], WTb[j * 32 + k], q);
            }
            pv[m] = a; qv[m] = q;
        }
        P4[j0 >> 2] = make_float4(pv[0], pv[1], pv[2], pv[3]);
        Q4[j0 >> 2] = make_float4(qv[0], qv[1], qv[2], qv[3]);
    }
}

// ---------- K_hist ----------
__global__ __launch_bounds__(256) void k_hist(const int* __restrict__ ei, u32* __restrict__ deg, int E) {
    int e = blockIdx.x * 256 + threadIdx.x;
    if (e >= E) return;
    atomicAdd(&deg[ei[E + e]], 1u);
}

// ---------- exclusive scan of deg -> cursor ----------
__global__ __launch_bounds__(256) void k_scan1(const u32* __restrict__ deg, u32* __restrict__ cursor,
                                               u32* __restrict__ bsum, int N) {
    __shared__ u32 sh[256];
    int t = threadIdx.x;
    int base = blockIdx.x * 1024 + t * 4;
    u32 v0 = 0, v1 = 0, v2 = 0, v3 = 0;
    if (base + 3 < N) {
        uint4 vv = *reinterpret_cast<const uint4*>(deg + base);
        v0 = vv.x; v1 = vv.y; v2 = vv.z; v3 = vv.w;
    } else {
        if (base < N) v0 = deg[base];
        if (base + 1 < N) v1 = deg[base + 1];
        if (base + 2 < N) v2 = deg[base + 2];
        if (base + 3 < N) v3 = deg[base + 3];
    }
    u32 s = v0 + v1 + v2 + v3;
    sh[t] = s; __syncthreads();
    u32 acc = s;
    for (int off = 1; off < 256; off <<= 1) {
        u32 add = (t >= off) ? sh[t - off] : 0;
        __syncthreads();
        acc += add; sh[t] = acc;
        __syncthreads();
    }
    u32 excl = acc - s;
    if (base < N) cursor[base] = excl;
    if (base + 1 < N) cursor[base + 1] = excl + v0;
    if (base + 2 < N) cursor[base + 2] = excl + v0 + v1;
    if (base + 3 < N) cursor[base + 3] = excl + v0 + v1 + v2;
    if (t == 255) bsum[blockIdx.x] = acc;
}

__global__ __launch_bounds__(256) void k_scan2(const u32* __restrict__ bsum, u32* __restrict__ bsumX, int nb) {
    __shared__ u32 sh[256];
    int t = threadIdx.x;
    u32 v = (t < nb) ? bsum[t] : 0;
    sh[t] = v; __syncthreads();
    u32 acc = v;
    for (int off = 1; off < 256; off <<= 1) {
        u32 add = (t >= off) ? sh[t - off] : 0;
        __syncthreads();
        acc += add; sh[t] = acc;
        __syncthreads();
    }
    if (t < nb) bsumX[t] = acc - v;
}

__global__ __launch_bounds__(256) void k_scan3(u32* __restrict__ cursor, const u32* __restrict__ bsumX, int N) {
    int i = blockIdx.x * 256 + threadIdx.x;
    if (i >= N) return;
    cursor[i] += bsumX[i >> 10];
}

// ---------- K_scatter: bucket edges by dst into packed (src,dst) pairs ----------
__global__ __launch_bounds__(256) void k_scatter(const int* __restrict__ ei, u32* __restrict__ cursor,
                                                 uint2* __restrict__ sd, int E) {
    int e = blockIdx.x * 256 + threadIdx.x;
    if (e >= E) return;
    int d = ei[E + e];
    int s = ei[e];
    u32 slot = atomicAdd(&cursor[d], 1u);
    sd[slot] = make_uint2((u32)s, (u32)d);
}

// ---------- K_pad: sentinel-pad the tail tile ----------
__global__ void k_pad(uint2* __restrict__ sd, int E, int Epad) {
    int i = E + threadIdx.x;
    if (i < Epad) sd[i] = make_uint2(0u, 0xFFFFFFFFu);
}

// ---------- K_edge_mfma: 16-edge tiles per wave, layer-2 GEMV via MFMA ----------
// A-frag (16x16x32 bf16): lane l holds A[row=l&15][k=(l>>4)*8 + j], j=0..7
// B-frag:                  lane l holds B[k=(l>>4)*8 + j][col=l&15]
// C/D  (m89-verified):     lane l, reg i -> D[row=(l>>4)*4+i][col=l&15]
__global__ __launch_bounds__(256) void k_edge_mfma(
    const float* __restrict__ P, const float* __restrict__ Q,
    const uint2* __restrict__ sd, const float* __restrict__ W2,
    u32* __restrict__ out, int tiles, int T)
{
    int lane = threadIdx.x & 63;
    int wave = blockIdx.x * 4 + (threadIdx.x >> 6);
    int n = lane & 15;     // B/D column
    int kc = lane >> 4;    // k-chunk
    int start = wave * T;
    if (start >= tiles) return;
    int end = min(start + T, tiles);

    // W2 resident as 4 B-fragments (bf16), loaded once
    short8v b00, b01, b10, b11;
#pragma unroll
    for (int j = 0; j < 8; ++j) {
        int k = kc * 8 + j;
        b00[j] = (short)bf16rne(W2[k * 32 + n]);
        b01[j] = (short)bf16rne(W2[(k + 32) * 32 + n]);
        b10[j] = (short)bf16rne(W2[k * 32 + n + 16]);
        b11[j] = (short)bf16rne(W2[(k + 32) * 32 + n + 16]);
    }

    int cur = -1;            // current dst run (carry across tiles)
    float m0 = 0.f, m1 = 0.f;

    for (int tile = start; tile < end; ++tile) {
        int base = tile * 16;
        // staging row r = n for this lane
        uint2 e = sd[base + n];
        int s = (int)e.x;
        int d = (int)e.y;
        int dsafe = (d < 0) ? 0 : d;
        const float* qp = Q + (size_t)s * 64 + kc * 8;
        const float* pp = P + (size_t)dsafe * 64 + kc * 8;
        f32x4 q0 = *(const f32x4*)(qp);
        f32x4 q1 = *(const f32x4*)(qp + 4);
        f32x4 q2 = *(const f32x4*)(qp + 32);
        f32x4 q3 = *(const f32x4*)(qp + 36);
        f32x4 p0 = *(const f32x4*)(pp);
        f32x4 p1 = *(const f32x4*)(pp + 4);
        f32x4 p2 = *(const f32x4*)(pp + 32);
        f32x4 p3 = *(const f32x4*)(pp + 36);

        short8v a0, a1;
#pragma unroll
        for (int j = 0; j < 4; ++j) {
            a0[j]     = (short)bf16rne(fmaxf(p0[j] + q0[j], 0.f));
            a0[j + 4] = (short)bf16rne(fmaxf(p1[j] + q1[j], 0.f));
            a1[j]     = (short)bf16rne(fmaxf(p2[j] + q2[j], 0.f));
            a1[j + 4] = (short)bf16rne(fmaxf(p3[j] + q3[j], 0.f));
        }

        f32x4 d0 = {0.f, 0.f, 0.f, 0.f};
        f32x4 d1 = {0.f, 0.f, 0.f, 0.f};
        d0 = __builtin_amdgcn_mfma_f32_16x16x32_bf16(a0, b00, d0, 0, 0, 0);
        d0 = __builtin_amdgcn_mfma_f32_16x16x32_bf16(a1, b01, d0, 0, 0, 0);
        d1 = __builtin_amdgcn_mfma_f32_16x16x32_bf16(a0, b10, d1, 0, 0, 0);
        d1 = __builtin_amdgcn_mfma_f32_16x16x32_bf16(a1, b11, d1, 0, 0, 0);

        // segmented max over sorted dst; this lane owns rows kc*4 + i
        int rb = base + kc * 4;
#pragma unroll
        for (int i = 0; i < 4; ++i) {
            int drow = (int)sd[rb + i].y;
            float v0 = d0[i], v1 = d1[i];
            if (drow != cur) {
                if (cur >= 0) {
                    u32* o = out + (size_t)cur * 32 + n;
                    atomicMax(o, enc_f32(m0));
                    atomicMax(o + 16, enc_f32(m1));
                }
                cur = drow; m0 = v0; m1 = v1;
            } else {
                m0 = fmaxf(m0, v0);
                m1 = fmaxf(m1, v1);
            }
        }
    }
    if (cur >= 0) {
        u32* o = out + (size_t)cur * 32 + n;
        atomicMax(o, enc_f32(m0));
        atomicMax(o + 16, enc_f32(m1));
    }
}

// ---------- K_decode: sentinel 0 -> 0.0 (no incoming edges), else decode + b2 ----------
__global__ __launch_bounds__(256) void k_decode(u32* __restrict__ buf, const float* __restrict__ b2, int n) {
    int i = blockIdx.x * 256 + threadIdx.x;
    if (i >= n) return;
    u32 u = buf[i];
    float f = u ? (dec_f32(u) + b2[i & 31]) : 0.f;
    reinterpret_cast<float*>(buf)[i] = f;
}

// ---------- fallback (round-1 style) ----------
__global__ __launch_bounds__(256) void fb_edge(const float* __restrict__ x, const int* __restrict__ ei,
                                               const float* __restrict__ W1, const float* __restrict__ b1,
                                               const float* __restrict__ W2, const float* __restrict__ b2,
                                               u32* __restrict__ out, int E) {
    int e = blockIdx.x * 256 + threadIdx.x;
    if (e >= E) return;
    int src = ei[e], dst = ei[E + e];
    float m[64];
    const float4* xi4 = reinterpret_cast<const float4*>(x + (size_t)dst * 32);
    const float4* xj4 = reinterpret_cast<const float4*>(x + (size_t)src * 32);
#pragma unroll
    for (int q = 0; q < 8; ++q) {
        float4 a = xi4[q], b = xj4[q];
        m[q * 4] = a.x; m[q * 4 + 1] = a.y; m[q * 4 + 2] = a.z; m[q * 4 + 3] = a.w;
        m[32 + q * 4] = b.x - a.x; m[32 + q * 4 + 1] = b.y - a.y;
        m[32 + q * 4 + 2] = b.z - a.z; m[32 + q * 4 + 3] = b.w - a.w;
    }
    float acc[32];
#pragma unroll
    for (int c = 0; c < 32; ++c) acc[c] = b2[c];
    for (int j = 0; j < 64; ++j) {
        float h = b1[j];
#pragma unroll
        for (int k = 0; k < 64; ++k) h = fmaf(m[k], W1[k * 64 + j], h);
        h = fmaxf(h, 0.0f);
#pragma unroll
        for (int c = 0; c < 32; ++c) acc[c] = fmaf(h, W2[j * 32 + c], acc[c]);
    }
    u32* o = out + (size_t)dst * 32;
#pragma unroll
    for (int c = 0; c < 32; ++c) atomicMax(o + c, enc_f32(acc[c]));
}
__global__ __launch_bounds__(256) void fb_decode(u32* __restrict__ buf, int n) {
    int i = blockIdx.x * 256 + threadIdx.x;
    if (i >= n) return;
    u32 u = buf[i];
    reinterpret_cast<float*>(buf)[i] = u ? dec_f32(u) : 0.f;
}

extern "C" void kernel_launch(void* const* d_in, const int* in_sizes, int n_in,
                              void* d_out, int out_size, void* d_ws, size_t ws_size,
                              hipStream_t stream) {
    const float* x  = (const float*)d_in[0];
    const int*   ei = (const int*)d_in[1];
    const float* W1 = (const float*)d_in[2];
    const float* b1 = (const float*)d_in[3];
    const float* W2 = (const float*)d_in[4];
    const float* b2 = (const float*)d_in[5];

    int N = in_sizes[0] / 32;
    int E = in_sizes[1] / 2;
    int Epad = (E + 15) & ~15;
    u32* out = (u32*)d_out;

    // workspace layout (256B aligned)
    char* ws = (char*)d_ws;
    size_t off = 0;
    auto alloc = [&](size_t bytes) { char* p = ws + off; off += (bytes + 255) & ~(size_t)255; return p; };
    float* WTa   = (float*)alloc(2048 * 4);
    float* WTb   = (float*)alloc(2048 * 4);
    float* P     = (float*)alloc((size_t)N * 64 * 4);
    float* Q     = (float*)alloc((size_t)N * 64 * 4);
    u32*   deg   = (u32*)alloc((size_t)N * 4);
    u32*   cur   = (u32*)alloc((size_t)N * 4);
    u32*   bsum  = (u32*)alloc(256 * 4);
    u32*   bsumX = (u32*)alloc(256 * 4);
    uint2* sd    = (uint2*)alloc((size_t)Epad * 8);
    bool fits = (off <= ws_size);

    hipMemsetAsync(d_out, 0, (size_t)out_size * 4, stream);

    if (!fits) {
        int be = (E + 255) / 256;
        fb_edge<<<be, 256, 0, stream>>>(x, ei, W1, b1, W2, b2, out, E);
        fb_decode<<<(out_size + 255) / 256, 256, 0, stream>>>(out, out_size);
        return;
    }

    hipMemsetAsync(deg, 0, (size_t)N * 4, stream);

    k_prep<<<1, 256, 0, stream>>>(W1, WTa, WTb);
    k_pq<<<(N + 255) / 256, 256, 0, stream>>>(x, WTa, WTb, b1, P, Q, N);

    int be = (E + 255) / 256;
    k_hist<<<be, 256, 0, stream>>>(ei, deg, E);

    int nb = (N + 1023) / 1024;  // must be <= 256
    k_scan1<<<nb, 256, 0, stream>>>(deg, cur, bsum, N);
    k_scan2<<<1, 256, 0, stream>>>(bsum, bsumX, nb);
    k_scan3<<<(N + 255) / 256, 256, 0, stream>>>(cur, bsumX, N);

    k_scatter<<<be, 256, 0, stream>>>(ei, cur, sd, E);
    if (Epad > E) k_pad<<<1, 64, 0, stream>>>(sd, E, Epad);

    int tiles = Epad / 16;
    int nblocks = 2048;                    // 4 waves each -> 8192 waves
    int nwaves = nblocks * 4;
    int T = (tiles + nwaves - 1) / nwaves; // tiles per wave
    k_edge_mfma<<<nblocks, 256, 0, stream>>>(P, Q, sd, W2, out, tiles, T);

    k_decode<<<(out_size + 255) / 256, 256, 0, stream>>>(out, b2, out_size);
}

// Round 4
// 244.640 us; speedup vs baseline: 8.6189x; 1.7326x over previous
//
#include <hip/hip_runtime.h>

typedef unsigned int u32;
typedef __attribute__((ext_vector_type(8))) short short8v;
typedef __attribute__((ext_vector_type(4))) float f32x4;

#define NPB 128          // nodes per bucket (must match shift below)
#define NPB_SHIFT 7
#define CH  8192         // edges per chunk for hist/scatter

// order-preserving float<->uint encoding; enc never returns 0 for real values
__device__ __forceinline__ u32 enc_f32(float f) {
    u32 b = __float_as_uint(f);
    return (b & 0x80000000u) ? ~b : (b | 0x80000000u);
}
__device__ __forceinline__ float dec_f32(u32 u) {
    u32 b = (u & 0x80000000u) ? (u & 0x7FFFFFFFu) : ~u;
    return __uint_as_float(b);
}
__device__ __forceinline__ unsigned short bf16rne(float f) {
    u32 u = __float_as_uint(f);
    u32 r = (u + 0x7FFFu + ((u >> 16) & 1u)) >> 16;
    return (unsigned short)r;
}

// ---------- K_prep: WTa[j][k] = W1[k][j]-W1[k+32][j], WTb[j][k] = W1[k+32][j] ----------
__global__ __launch_bounds__(256) void k_prep(const float* __restrict__ W1,
                                              float* __restrict__ WTa, float* __restrict__ WTb) {
    for (int idx = threadIdx.x; idx < 2048; idx += 256) {
        int j = idx >> 5, k = idx & 31;
        float a = W1[k * 64 + j];
        float b = W1[(k + 32) * 64 + j];
        WTa[j * 32 + k] = a - b;
        WTb[j * 32 + k] = b;
    }
}

// ---------- K_pq: per-node tables P = x@(W1a-W1b)+b1, Q = x@W1b ----------
__global__ __launch_bounds__(256) void k_pq(const float* __restrict__ x,
                                            const float* __restrict__ WTa,
                                            const float* __restrict__ WTb,
                                            const float* __restrict__ b1,
                                            float* __restrict__ P, float* __restrict__ Q, int N) {
    int n = blockIdx.x * 256 + threadIdx.x;
    if (n >= N) return;
    float xr[32];
    const float4* x4 = reinterpret_cast<const float4*>(x + (size_t)n * 32);
#pragma unroll
    for (int q = 0; q < 8; ++q) {
        float4 v = x4[q];
        xr[4 * q] = v.x; xr[4 * q + 1] = v.y; xr[4 * q + 2] = v.z; xr[4 * q + 3] = v.w;
    }
    float4* P4 = reinterpret_cast<float4*>(P + (size_t)n * 64);
    float4* Q4 = reinterpret_cast<float4*>(Q + (size_t)n * 64);
    for (int j0 = 0; j0 < 64; j0 += 4) {
        float pv[4], qv[4];
#pragma unroll
        for (int m = 0; m < 4; ++m) {
            int j = j0 + m;
            float a = b1[j], q = 0.f;
#pragma unroll
            for (int k = 0; k < 32; ++k) {
                a = fmaf(xr[k], WTa[j * 32 + k], a);
                q = fmaf(xr[k], WTb[j * 32 + k], q);
            }
            pv[m] = a; qv[m] = q;
        }
        P4[j0 >> 2] = make_float4(pv[0], pv[1], pv[2], pv[3]);
        Q4[j0 >> 2] = make_float4(qv[0], qv[1], qv[2], qv[3]);
    }
}

// ---------- K_hist2: per-(chunk,bucket) counts, bucket-major: gh[b*nchunks + c] ----------
__global__ __launch_bounds__(256) void k_hist2(const int* __restrict__ ei, u32* __restrict__ gh,
                                               int E, int NB, int nchunks) {
    extern __shared__ u32 cnt[];   // [NB]
    int c = blockIdx.x;
    for (int b = threadIdx.x; b < NB; b += 256) cnt[b] = 0;
    __syncthreads();
    int s0 = c * CH, end = min(E, s0 + CH);
    for (int e = s0 + threadIdx.x; e < end; e += 256) {
        int d = ei[E + e];
        atomicAdd(&cnt[d >> NPB_SHIFT], 1u);
    }
    __syncthreads();
    for (int b = threadIdx.x; b < NB; b += 256) gh[(size_t)b * nchunks + c] = cnt[b];
}

// ---------- exclusive scan (generic, 3 kernels, 1024 items/block) ----------
__global__ __launch_bounds__(256) void k_scan1(const u32* __restrict__ deg, u32* __restrict__ cursor,
                                               u32* __restrict__ bsum, int N) {
    __shared__ u32 sh[256];
    int t = threadIdx.x;
    int base = blockIdx.x * 1024 + t * 4;
    u32 v0 = 0, v1 = 0, v2 = 0, v3 = 0;
    if (base + 3 < N) {
        uint4 vv = *reinterpret_cast<const uint4*>(deg + base);
        v0 = vv.x; v1 = vv.y; v2 = vv.z; v3 = vv.w;
    } else {
        if (base < N) v0 = deg[base];
        if (base + 1 < N) v1 = deg[base + 1];
        if (base + 2 < N) v2 = deg[base + 2];
        if (base + 3 < N) v3 = deg[base + 3];
    }
    u32 s = v0 + v1 + v2 + v3;
    sh[t] = s; __syncthreads();
    u32 acc = s;
    for (int off = 1; off < 256; off <<= 1) {
        u32 add = (t >= off) ? sh[t - off] : 0;
        __syncthreads();
        acc += add; sh[t] = acc;
        __syncthreads();
    }
    u32 excl = acc - s;
    if (base < N) cursor[base] = excl;
    if (base + 1 < N) cursor[base + 1] = excl + v0;
    if (base + 2 < N) cursor[base + 2] = excl + v0 + v1;
    if (base + 3 < N) cursor[base + 3] = excl + v0 + v1 + v2;
    if (t == 255) bsum[blockIdx.x] = acc;
}

__global__ __launch_bounds__(256) void k_scan2(const u32* __restrict__ bsum, u32* __restrict__ bsumX, int nb) {
    __shared__ u32 sh[256];
    int t = threadIdx.x;
    u32 v = (t < nb) ? bsum[t] : 0;
    sh[t] = v; __syncthreads();
    u32 acc = v;
    for (int off = 1; off < 256; off <<= 1) {
        u32 add = (t >= off) ? sh[t - off] : 0;
        __syncthreads();
        acc += add; sh[t] = acc;
        __syncthreads();
    }
    if (t < nb) bsumX[t] = acc - v;
}

__global__ __launch_bounds__(256) void k_scan3(u32* __restrict__ cursor, const u32* __restrict__ bsumX, int N) {
    int i = blockIdx.x * 256 + threadIdx.x;
    if (i >= N) return;
    cursor[i] += bsumX[i >> 10];
}

// ---------- K_scatter2: bucket edges, slot = base[b][chunk] + LDS-rank ----------
// payload: src (17b) | local (7b) << 17
__global__ __launch_bounds__(256) void k_scatter2(const int* __restrict__ ei, const u32* __restrict__ gcur,
                                                  u32* __restrict__ sorted, int E, int NB, int nchunks) {
    extern __shared__ u32 sh[];    // [NB] base, [NB] cnt
    u32* base = sh;
    u32* cnt  = sh + NB;
    int c = blockIdx.x;
    for (int b = threadIdx.x; b < NB; b += 256) {
        base[b] = gcur[(size_t)b * nchunks + c];
        cnt[b] = 0;
    }
    __syncthreads();
    int s0 = c * CH, end = min(E, s0 + CH);
    for (int e = s0 + threadIdx.x; e < end; e += 256) {
        int d = ei[E + e];
        int s = ei[e];
        int b = d >> NPB_SHIFT;
        u32 r = atomicAdd(&cnt[b], 1u);
        sorted[base[b] + r] = (u32)s | ((u32)(d & (NPB - 1)) << 17);
    }
}

// ---------- K_bucket: one block per bucket; MFMA layer-2 + LDS max-agg; final write fused ----------
// A-frag (16x16x32 bf16): lane l holds A[row=l&15][k=(l>>4)*8 + j]
// C/D (m89-verified):     lane l, reg i -> D[row=(l>>4)*4+i][col=l&15]
__global__ __launch_bounds__(256) void k_bucket(
    const float* __restrict__ P, const float* __restrict__ Q,
    const u32* __restrict__ sorted, const u32* __restrict__ gcur,
    const float* __restrict__ W2, const float* __restrict__ b2,
    float* __restrict__ out, int E, int N, int NB, int nchunks)
{
    __shared__ u32 agg[NPB * 32];   // 16 KB, encoded-u32 max, 0 = "untouched"
    int b = blockIdx.x;
    int tid = threadIdx.x;
    for (int i = tid; i < NPB * 32; i += 256) agg[i] = 0u;

    int lane = tid & 63;
    int wid = tid >> 6;
    int n = lane & 15;
    int kc = lane >> 4;

    // W2 resident as 4 bf16 B-fragments
    short8v b00, b01, b10, b11;
#pragma unroll
    for (int j = 0; j < 8; ++j) {
        int k = kc * 8 + j;
        b00[j] = (short)bf16rne(W2[k * 32 + n]);
        b01[j] = (short)bf16rne(W2[(k + 32) * 32 + n]);
        b10[j] = (short)bf16rne(W2[k * 32 + n + 16]);
        b11[j] = (short)bf16rne(W2[(k + 32) * 32 + n + 16]);
    }

    u32 start = gcur[(size_t)b * nchunks];
    u32 bend  = (b + 1 < NB) ? gcur[(size_t)(b + 1) * nchunks] : (u32)E;
    int deg = (int)(bend - start);
    int ntiles = (deg + 15) >> 4;
    int nodebase = b * NPB;

    __syncthreads();

    for (int tile = wid; tile < ntiles; tile += 4) {
        u32 slot = start + (u32)tile * 16u + (u32)n;
        bool valid = slot < bend;
        u32 rec = sorted[valid ? slot : (bend - 1)];
        int src = (int)(rec & 0x1FFFFu);
        int local = valid ? (int)(rec >> 17) : -1;
        int prow = nodebase + (valid ? local : 0);

        const float* qp = Q + (size_t)src * 64 + kc * 8;
        const float* pp = P + (size_t)prow * 64 + kc * 8;
        f32x4 q0 = *(const f32x4*)(qp);
        f32x4 q1 = *(const f32x4*)(qp + 4);
        f32x4 q2 = *(const f32x4*)(qp + 32);
        f32x4 q3 = *(const f32x4*)(qp + 36);
        f32x4 p0 = *(const f32x4*)(pp);
        f32x4 p1 = *(const f32x4*)(pp + 4);
        f32x4 p2 = *(const f32x4*)(pp + 32);
        f32x4 p3 = *(const f32x4*)(pp + 36);

        short8v a0, a1;
#pragma unroll
        for (int j = 0; j < 4; ++j) {
            a0[j]     = (short)bf16rne(fmaxf(p0[j] + q0[j], 0.f));
            a0[j + 4] = (short)bf16rne(fmaxf(p1[j] + q1[j], 0.f));
            a1[j]     = (short)bf16rne(fmaxf(p2[j] + q2[j], 0.f));
            a1[j + 4] = (short)bf16rne(fmaxf(p3[j] + q3[j], 0.f));
        }

        f32x4 d0 = {0.f, 0.f, 0.f, 0.f};
        f32x4 d1 = {0.f, 0.f, 0.f, 0.f};
        d0 = __builtin_amdgcn_mfma_f32_16x16x32_bf16(a0, b00, d0, 0, 0, 0);
        d0 = __builtin_amdgcn_mfma_f32_16x16x32_bf16(a1, b01, d0, 0, 0, 0);
        d1 = __builtin_amdgcn_mfma_f32_16x16x32_bf16(a0, b10, d1, 0, 0, 0);
        d1 = __builtin_amdgcn_mfma_f32_16x16x32_bf16(a1, b11, d1, 0, 0, 0);

        // rows owned by this lane: r = kc*4 + i; row r's record lives in lane r
#pragma unroll
        for (int i = 0; i < 4; ++i) {
            int r = kc * 4 + i;
            int lr = __shfl(local, r, 64);
            if (lr >= 0) {
                atomicMax(&agg[lr * 32 + n], enc_f32(d0[i]));
                atomicMax(&agg[lr * 32 + n + 16], enc_f32(d1[i]));
            }
        }
    }

    __syncthreads();
    // fused decode + b2 + empty->0; every node written exactly once (no d_out memset needed)
    for (int i = tid; i < NPB * 32; i += 256) {
        int local = i >> 5, c = i & 31;
        int node = nodebase + local;
        if (node < N) {
            u32 u = agg[i];
            out[(size_t)node * 32 + c] = u ? (dec_f32(u) + b2[c]) : 0.f;
        }
    }
}

// ---------- fallback (round-1 style) ----------
__global__ __launch_bounds__(256) void fb_edge(const float* __restrict__ x, const int* __restrict__ ei,
                                               const float* __restrict__ W1, const float* __restrict__ b1,
                                               const float* __restrict__ W2, const float* __restrict__ b2,
                                               u32* __restrict__ out, int E) {
    int e = blockIdx.x * 256 + threadIdx.x;
    if (e >= E) return;
    int src = ei[e], dst = ei[E + e];
    float m[64];
    const float4* xi4 = reinterpret_cast<const float4*>(x + (size_t)dst * 32);
    const float4* xj4 = reinterpret_cast<const float4*>(x + (size_t)src * 32);
#pragma unroll
    for (int q = 0; q < 8; ++q) {
        float4 a = xi4[q], b = xj4[q];
        m[q * 4] = a.x; m[q * 4 + 1] = a.y; m[q * 4 + 2] = a.z; m[q * 4 + 3] = a.w;
        m[32 + q * 4] = b.x - a.x; m[32 + q * 4 + 1] = b.y - a.y;
        m[32 + q * 4 + 2] = b.z - a.z; m[32 + q * 4 + 3] = b.w - a.w;
    }
    float acc[32];
#pragma unroll
    for (int c = 0; c < 32; ++c) acc[c] = b2[c];
    for (int j = 0; j < 64; ++j) {
        float h = b1[j];
#pragma unroll
        for (int k = 0; k < 64; ++k) h = fmaf(m[k], W1[k * 64 + j], h);
        h = fmaxf(h, 0.0f);
#pragma unroll
        for (int c = 0; c < 32; ++c) acc[c] = fmaf(h, W2[j * 32 + c], acc[c]);
    }
    u32* o = out + (size_t)dst * 32;
#pragma unroll
    for (int c = 0; c < 32; ++c) atomicMax(o + c, enc_f32(acc[c]));
}
__global__ __launch_bounds__(256) void fb_decode(u32* __restrict__ buf, int n) {
    int i = blockIdx.x * 256 + threadIdx.x;
    if (i >= n) return;
    u32 u = buf[i];
    reinterpret_cast<float*>(buf)[i] = u ? dec_f32(u) : 0.f;
}

extern "C" void kernel_launch(void* const* d_in, const int* in_sizes, int n_in,
                              void* d_out, int out_size, void* d_ws, size_t ws_size,
                              hipStream_t stream) {
    const float* x  = (const float*)d_in[0];
    const int*   ei = (const int*)d_in[1];
    const float* W1 = (const float*)d_in[2];
    const float* b1 = (const float*)d_in[3];
    const float* W2 = (const float*)d_in[4];
    const float* b2 = (const float*)d_in[5];

    int N = in_sizes[0] / 32;
    int E = in_sizes[1] / 2;
    int NB = (N + NPB - 1) / NPB;           // 782 for N=100000
    int nchunks = (E + CH - 1) / CH;        // 196 for E=1.6M
    int M = NB * nchunks;                   // flat hist size

    // workspace layout (256B aligned)
    char* ws = (char*)d_ws;
    size_t off = 0;
    auto alloc = [&](size_t bytes) { char* p = ws + off; off += (bytes + 255) & ~(size_t)255; return p; };
    float* WTa    = (float*)alloc(2048 * 4);
    float* WTb    = (float*)alloc(2048 * 4);
    float* P      = (float*)alloc((size_t)N * 64 * 4);
    float* Q      = (float*)alloc((size_t)N * 64 * 4);
    u32*   gh     = (u32*)alloc((size_t)M * 4);
    u32*   gcur   = (u32*)alloc((size_t)M * 4);
    u32*   bsum   = (u32*)alloc(256 * 4);
    u32*   bsumX  = (u32*)alloc(256 * 4);
    u32*   sorted = (u32*)alloc((size_t)E * 4);
    bool fits = (off <= ws_size) && (((M + 1023) / 1024) <= 256);

    if (!fits) {
        hipMemsetAsync(d_out, 0, (size_t)out_size * 4, stream);
        int be = (E + 255) / 256;
        fb_edge<<<be, 256, 0, stream>>>(x, ei, W1, b1, W2, b2, (u32*)d_out, E);
        fb_decode<<<(out_size + 255) / 256, 256, 0, stream>>>((u32*)d_out, out_size);
        return;
    }

    k_prep<<<1, 256, 0, stream>>>(W1, WTa, WTb);
    k_pq<<<(N + 255) / 256, 256, 0, stream>>>(x, WTa, WTb, b1, P, Q, N);

    k_hist2<<<nchunks, 256, (size_t)NB * 4, stream>>>(ei, gh, E, NB, nchunks);

    int nb = (M + 1023) / 1024;
    k_scan1<<<nb, 256, 0, stream>>>(gh, gcur, bsum, M);
    k_scan2<<<1, 256, 0, stream>>>(bsum, bsumX, nb);
    k_scan3<<<(M + 255) / 256, 256, 0, stream>>>(gcur, bsumX, M);

    k_scatter2<<<nchunks, 256, (size_t)NB * 8, stream>>>(ei, gcur, sorted, E, NB, nchunks);

    k_bucket<<<NB, 256, 0, stream>>>(P, Q, sorted, gcur, W2, b2, (float*)d_out, E, N, NB, nchunks);
}

// Round 5
// 188.154 us; speedup vs baseline: 11.2063x; 1.3002x over previous
//
#include <hip/hip_runtime.h>

typedef unsigned int u32;
typedef __attribute__((ext_vector_type(8))) short short8v;
typedef __attribute__((ext_vector_type(4))) float f32x4;

#define NPB 64           // nodes per bucket
#define NPB_SHIFT 6
#define CH  16384        // edges per chunk for hist/scatter

// order-preserving float<->uint encoding; enc never returns 0 for real values
__device__ __forceinline__ u32 enc_f32(float f) {
    u32 b = __float_as_uint(f);
    return (b & 0x80000000u) ? ~b : (b | 0x80000000u);
}
__device__ __forceinline__ float dec_f32(u32 u) {
    u32 b = (u & 0x80000000u) ? (u & 0x7FFFFFFFu) : ~u;
    return __uint_as_float(b);
}
__device__ __forceinline__ unsigned short bf16rne(float f) {
    u32 u = __float_as_uint(f);
    u32 r = (u + 0x7FFFu + ((u >> 16) & 1u)) >> 16;
    return (unsigned short)r;
}
__device__ __forceinline__ float bflo(u32 u) { return __uint_as_float(u << 16); }
__device__ __forceinline__ float bfhi(u32 u) { return __uint_as_float(u & 0xFFFF0000u); }

// ---------- K_pq: fused weight transpose (LDS) + per-node tables ----------
// P = x@(W1a-W1b)+b1 (f32), Qb = bf16(x@W1b) packed 2/u32
__global__ __launch_bounds__(256) void k_pq(const float* __restrict__ x,
                                            const float* __restrict__ W1,
                                            const float* __restrict__ b1,
                                            float* __restrict__ P, u32* __restrict__ Qb, int N) {
    __shared__ float sWTa[2048];   // [j][k] = W1[k][j]-W1[k+32][j]
    __shared__ float sWTb[2048];   // [j][k] = W1[k+32][j]
    for (int idx = threadIdx.x; idx < 2048; idx += 256) {
        int j = idx >> 5, k = idx & 31;
        float a = W1[k * 64 + j];
        float b = W1[(k + 32) * 64 + j];
        sWTa[j * 32 + k] = a - b;
        sWTb[j * 32 + k] = b;
    }
    __syncthreads();

    int n = blockIdx.x * 256 + threadIdx.x;
    if (n >= N) return;
    float xr[32];
    const float4* x4 = reinterpret_cast<const float4*>(x + (size_t)n * 32);
#pragma unroll
    for (int q = 0; q < 8; ++q) {
        float4 v = x4[q];
        xr[4 * q] = v.x; xr[4 * q + 1] = v.y; xr[4 * q + 2] = v.z; xr[4 * q + 3] = v.w;
    }
    float4* P4 = reinterpret_cast<float4*>(P + (size_t)n * 64);
    uint2* Q2 = reinterpret_cast<uint2*>(Qb + (size_t)n * 32);
    for (int j0 = 0; j0 < 64; j0 += 4) {
        float pv[4], qv[4];
#pragma unroll
        for (int m = 0; m < 4; ++m) {
            int j = j0 + m;
            float a = b1[j], q = 0.f;
#pragma unroll
            for (int k = 0; k < 32; ++k) {
                a = fmaf(xr[k], sWTa[j * 32 + k], a);
                q = fmaf(xr[k], sWTb[j * 32 + k], q);
            }
            pv[m] = a; qv[m] = q;
        }
        P4[j0 >> 2] = make_float4(pv[0], pv[1], pv[2], pv[3]);
        u32 lo = (u32)bf16rne(qv[0]) | ((u32)bf16rne(qv[1]) << 16);
        u32 hi = (u32)bf16rne(qv[2]) | ((u32)bf16rne(qv[3]) << 16);
        Q2[j0 >> 2] = make_uint2(lo, hi);
    }
}

// ---------- K_hist2: per-(chunk,bucket) counts, bucket-major: gh[b*nchunks + c] ----------
__global__ __launch_bounds__(256) void k_hist2(const int* __restrict__ ei, u32* __restrict__ gh,
                                               int E, int NB, int nchunks) {
    extern __shared__ u32 cnt[];   // [NB]
    int c = blockIdx.x;
    for (int b = threadIdx.x; b < NB; b += 256) cnt[b] = 0;
    __syncthreads();
    int s0 = c * CH, end = min(E, s0 + CH);
    for (int e = s0 + threadIdx.x; e < end; e += 256) {
        int d = ei[E + e];
        atomicAdd(&cnt[d >> NPB_SHIFT], 1u);
    }
    __syncthreads();
    for (int b = threadIdx.x; b < NB; b += 256) gh[(size_t)b * nchunks + c] = cnt[b];
}

// ---------- exclusive scan, partial (1024/block) + block sums ----------
__global__ __launch_bounds__(256) void k_scan1(const u32* __restrict__ deg, u32* __restrict__ cursor,
                                               u32* __restrict__ bsum, int N) {
    __shared__ u32 sh[256];
    int t = threadIdx.x;
    int base = blockIdx.x * 1024 + t * 4;
    u32 v0 = 0, v1 = 0, v2 = 0, v3 = 0;
    if (base + 3 < N) {
        uint4 vv = *reinterpret_cast<const uint4*>(deg + base);
        v0 = vv.x; v1 = vv.y; v2 = vv.z; v3 = vv.w;
    } else {
        if (base < N) v0 = deg[base];
        if (base + 1 < N) v1 = deg[base + 1];
        if (base + 2 < N) v2 = deg[base + 2];
        if (base + 3 < N) v3 = deg[base + 3];
    }
    u32 s = v0 + v1 + v2 + v3;
    sh[t] = s; __syncthreads();
    u32 acc = s;
    for (int off = 1; off < 256; off <<= 1) {
        u32 add = (t >= off) ? sh[t - off] : 0;
        __syncthreads();
        acc += add; sh[t] = acc;
        __syncthreads();
    }
    u32 excl = acc - s;
    if (base < N) cursor[base] = excl;
    if (base + 1 < N) cursor[base + 1] = excl + v0;
    if (base + 2 < N) cursor[base + 2] = excl + v0 + v1;
    if (base + 3 < N) cursor[base + 3] = excl + v0 + v1 + v2;
    if (t == 255) bsum[blockIdx.x] = acc;
}

__global__ __launch_bounds__(256) void k_scan2(const u32* __restrict__ bsum, u32* __restrict__ bsumX, int nb) {
    __shared__ u32 sh[256];
    int t = threadIdx.x;
    u32 v = (t < nb) ? bsum[t] : 0;
    sh[t] = v; __syncthreads();
    u32 acc = v;
    for (int off = 1; off < 256; off <<= 1) {
        u32 add = (t >= off) ? sh[t - off] : 0;
        __syncthreads();
        acc += add; sh[t] = acc;
        __syncthreads();
    }
    if (t < nb) bsumX[t] = acc - v;
}

// ---------- K_scatter2: bucket edges, slot = (gcur+bsumX)[b][chunk] + LDS-rank ----------
// payload: src (17b) | local (6b) << 17
__global__ __launch_bounds__(256) void k_scatter2(const int* __restrict__ ei, const u32* __restrict__ gcur,
                                                  const u32* __restrict__ bsumX,
                                                  u32* __restrict__ sorted, int E, int NB, int nchunks) {
    extern __shared__ u32 sh[];    // [NB] base, [NB] cnt
    u32* base = sh;
    u32* cnt  = sh + NB;
    int c = blockIdx.x;
    for (int b = threadIdx.x; b < NB; b += 256) {
        size_t idx = (size_t)b * nchunks + c;
        base[b] = gcur[idx] + bsumX[idx >> 10];
        cnt[b] = 0;
    }
    __syncthreads();
    int s0 = c * CH, end = min(E, s0 + CH);
    for (int e = s0 + threadIdx.x; e < end; e += 256) {
        int d = ei[E + e];
        int s = ei[e];
        int b = d >> NPB_SHIFT;
        u32 r = atomicAdd(&cnt[b], 1u);
        sorted[base[b] + r] = (u32)s | ((u32)(d & (NPB - 1)) << 17);
    }
}

// ---------- K_bucket: one block per bucket; MFMA layer-2 + LDS max-agg; fused final write ----------
// A-frag (16x16x32 bf16): lane l holds A[row=l&15][k=(l>>4)*8 + j] (linear j=0..7)
// C/D (m89-verified):     lane l, reg i -> D[row=(l>>4)*4+i][col=l&15]
__global__ __launch_bounds__(256) void k_bucket(
    const float* __restrict__ P, const u32* __restrict__ Qb,
    const u32* __restrict__ sorted, const u32* __restrict__ gcur,
    const u32* __restrict__ bsumX,
    const float* __restrict__ W2, const float* __restrict__ b2,
    float* __restrict__ out, int E, int N, int NB, int nchunks)
{
    __shared__ u32 agg[NPB * 32];   // 8 KB, encoded-u32 max, 0 = "untouched"
    int b = blockIdx.x;
    int tid = threadIdx.x;
    for (int i = tid; i < NPB * 32; i += 256) agg[i] = 0u;

    int lane = tid & 63;
    int wid = tid >> 6;
    int n = lane & 15;
    int kc = lane >> 4;

    // W2 resident as 4 bf16 B-fragments
    short8v b00, b01, b10, b11;
#pragma unroll
    for (int j = 0; j < 8; ++j) {
        int k = kc * 8 + j;
        b00[j] = (short)bf16rne(W2[k * 32 + n]);
        b01[j] = (short)bf16rne(W2[(k + 32) * 32 + n]);
        b10[j] = (short)bf16rne(W2[k * 32 + n + 16]);
        b11[j] = (short)bf16rne(W2[(k + 32) * 32 + n + 16]);
    }

    size_t i0 = (size_t)b * nchunks;
    u32 start = gcur[i0] + bsumX[i0 >> 10];
    u32 bend;
    if (b + 1 < NB) {
        size_t i1 = (size_t)(b + 1) * nchunks;
        bend = gcur[i1] + bsumX[i1 >> 10];
    } else {
        bend = (u32)E;
    }
    int deg = (int)(bend - start);
    int ntiles = (deg + 15) >> 4;
    int nodebase = b * NPB;

    __syncthreads();

    for (int tile = wid; tile < ntiles; tile += 4) {
        u32 slot = start + (u32)tile * 16u + (u32)n;
        bool valid = slot < bend;
        u32 rec = sorted[valid ? slot : (bend - 1)];
        int src = (int)(rec & 0x1FFFFu);
        int local = valid ? (int)(rec >> 17) : -1;
        int prow = nodebase + (valid ? local : 0);

        const float* pp = P + (size_t)prow * 64 + kc * 8;
        f32x4 p0 = *(const f32x4*)(pp);
        f32x4 p1 = *(const f32x4*)(pp + 4);
        f32x4 p2 = *(const f32x4*)(pp + 32);
        f32x4 p3 = *(const f32x4*)(pp + 36);
        const u32* qrow = Qb + (size_t)src * 32;
        uint4 qA = *(const uint4*)(qrow + kc * 4);
        uint4 qB = *(const uint4*)(qrow + 16 + kc * 4);

        float pl[8] = {p0[0], p0[1], p0[2], p0[3], p1[0], p1[1], p1[2], p1[3]};
        float ph[8] = {p2[0], p2[1], p2[2], p2[3], p3[0], p3[1], p3[2], p3[3]};
        u32 qa[4] = {qA.x, qA.y, qA.z, qA.w};
        u32 qb[4] = {qB.x, qB.y, qB.z, qB.w};

        short8v a0, a1;
#pragma unroll
        for (int t = 0; t < 4; ++t) {
            a0[2 * t]     = (short)bf16rne(fmaxf(pl[2 * t] + bflo(qa[t]), 0.f));
            a0[2 * t + 1] = (short)bf16rne(fmaxf(pl[2 * t + 1] + bfhi(qa[t]), 0.f));
            a1[2 * t]     = (short)bf16rne(fmaxf(ph[2 * t] + bflo(qb[t]), 0.f));
            a1[2 * t + 1] = (short)bf16rne(fmaxf(ph[2 * t + 1] + bfhi(qb[t]), 0.f));
        }

        f32x4 d0 = {0.f, 0.f, 0.f, 0.f};
        f32x4 d1 = {0.f, 0.f, 0.f, 0.f};
        d0 = __builtin_amdgcn_mfma_f32_16x16x32_bf16(a0, b00, d0, 0, 0, 0);
        d0 = __builtin_amdgcn_mfma_f32_16x16x32_bf16(a1, b01, d0, 0, 0, 0);
        d1 = __builtin_amdgcn_mfma_f32_16x16x32_bf16(a0, b10, d1, 0, 0, 0);
        d1 = __builtin_amdgcn_mfma_f32_16x16x32_bf16(a1, b11, d1, 0, 0, 0);

        // rows owned by this lane: r = kc*4 + i; row r's record lives in lane r
#pragma unroll
        for (int i = 0; i < 4; ++i) {
            int r = kc * 4 + i;
            int lr = __shfl(local, r, 64);
            if (lr >= 0) {
                atomicMax(&agg[lr * 32 + n], enc_f32(d0[i]));
                atomicMax(&agg[lr * 32 + n + 16], enc_f32(d1[i]));
            }
        }
    }

    __syncthreads();
    // fused decode + b2 + empty->0; every node written exactly once
    for (int i = tid; i < NPB * 32; i += 256) {
        int local = i >> 5, c = i & 31;
        int node = nodebase + local;
        if (node < N) {
            u32 u = agg[i];
            out[(size_t)node * 32 + c] = u ? (dec_f32(u) + b2[c]) : 0.f;
        }
    }
}

// ---------- fallback (round-1 style) ----------
__global__ __launch_bounds__(256) void fb_edge(const float* __restrict__ x, const int* __restrict__ ei,
                                               const float* __restrict__ W1, const float* __restrict__ b1,
                                               const float* __restrict__ W2, const float* __restrict__ b2,
                                               u32* __restrict__ out, int E) {
    int e = blockIdx.x * 256 + threadIdx.x;
    if (e >= E) return;
    int src = ei[e], dst = ei[E + e];
    float m[64];
    const float4* xi4 = reinterpret_cast<const float4*>(x + (size_t)dst * 32);
    const float4* xj4 = reinterpret_cast<const float4*>(x + (size_t)src * 32);
#pragma unroll
    for (int q = 0; q < 8; ++q) {
        float4 a = xi4[q], b = xj4[q];
        m[q * 4] = a.x; m[q * 4 + 1] = a.y; m[q * 4 + 2] = a.z; m[q * 4 + 3] = a.w;
        m[32 + q * 4] = b.x - a.x; m[32 + q * 4 + 1] = b.y - a.y;
        m[32 + q * 4 + 2] = b.z - a.z; m[32 + q * 4 + 3] = b.w - a.w;
    }
    float acc[32];
#pragma unroll
    for (int c = 0; c < 32; ++c) acc[c] = b2[c];
    for (int j = 0; j < 64; ++j) {
        float h = b1[j];
#pragma unroll
        for (int k = 0; k < 64; ++k) h = fmaf(m[k], W1[k * 64 + j], h);
        h = fmaxf(h, 0.0f);
#pragma unroll
        for (int c = 0; c < 32; ++c) acc[c] = fmaf(h, W2[j * 32 + c], acc[c]);
    }
    u32* o = out + (size_t)dst * 32;
#pragma unroll
    for (int c = 0; c < 32; ++c) atomicMax(o + c, enc_f32(acc[c]));
}
__global__ __launch_bounds__(256) void fb_decode(u32* __restrict__ buf, int n) {
    int i = blockIdx.x * 256 + threadIdx.x;
    if (i >= n) return;
    u32 u = buf[i];
    reinterpret_cast<float*>(buf)[i] = u ? dec_f32(u) : 0.f;
}

extern "C" void kernel_launch(void* const* d_in, const int* in_sizes, int n_in,
                              void* d_out, int out_size, void* d_ws, size_t ws_size,
                              hipStream_t stream) {
    const float* x  = (const float*)d_in[0];
    const int*   ei = (const int*)d_in[1];
    const float* W1 = (const float*)d_in[2];
    const float* b1 = (const float*)d_in[3];
    const float* W2 = (const float*)d_in[4];
    const float* b2 = (const float*)d_in[5];

    int N = in_sizes[0] / 32;
    int E = in_sizes[1] / 2;
    int NB = (N + NPB - 1) / NPB;           // 1563 for N=100000
    int nchunks = (E + CH - 1) / CH;        // 98 for E=1.6M
    int M = NB * nchunks;                   // flat hist size (153174)

    // workspace layout (256B aligned)
    char* ws = (char*)d_ws;
    size_t off = 0;
    auto alloc = [&](size_t bytes) { char* p = ws + off; off += (bytes + 255) & ~(size_t)255; return p; };
    float* P      = (float*)alloc((size_t)N * 64 * 4);
    u32*   Qb     = (u32*)alloc((size_t)N * 32 * 4);
    u32*   gh     = (u32*)alloc((size_t)M * 4);
    u32*   gcur   = (u32*)alloc((size_t)M * 4);
    u32*   bsum   = (u32*)alloc(256 * 4);
    u32*   bsumX  = (u32*)alloc(256 * 4);
    u32*   sorted = (u32*)alloc((size_t)E * 4);
    int nb = (M + 1023) / 1024;
    bool fits = (off <= ws_size) && (nb <= 256) && (N < (1 << 17));

    if (!fits) {
        hipMemsetAsync(d_out, 0, (size_t)out_size * 4, stream);
        int be = (E + 255) / 256;
        fb_edge<<<be, 256, 0, stream>>>(x, ei, W1, b1, W2, b2, (u32*)d_out, E);
        fb_decode<<<(out_size + 255) / 256, 256, 0, stream>>>((u32*)d_out, out_size);
        return;
    }

    k_pq<<<(N + 255) / 256, 256, 0, stream>>>(x, W1, b1, P, Qb, N);

    k_hist2<<<nchunks, 256, (size_t)NB * 4, stream>>>(ei, gh, E, NB, nchunks);

    k_scan1<<<nb, 256, 0, stream>>>(gh, gcur, bsum, M);
    k_scan2<<<1, 256, 0, stream>>>(bsum, bsumX, nb);

    k_scatter2<<<nchunks, 256, (size_t)NB * 8, stream>>>(ei, gcur, bsumX, sorted, E, NB, nchunks);

    k_bucket<<<NB, 256, 0, stream>>>(P, Qb, sorted, gcur, bsumX, W2, b2, (float*)d_out, E, N, NB, nchunks);
}

// Round 6
// 179.348 us; speedup vs baseline: 11.7566x; 1.0491x over previous
//
#include <hip/hip_runtime.h>

typedef unsigned int u32;
typedef __attribute__((ext_vector_type(8))) short short8v;
typedef __attribute__((ext_vector_type(4))) float f32x4;

#define NPB 32           // nodes per bucket
#define NPB_SHIFT 5
#define CH  32768        // edges per chunk for hist/scatter

// order-preserving float<->uint encoding; enc never returns 0 for real values
__device__ __forceinline__ u32 enc_f32(float f) {
    u32 b = __float_as_uint(f);
    return (b & 0x80000000u) ? ~b : (b | 0x80000000u);
}
__device__ __forceinline__ float dec_f32(u32 u) {
    u32 b = (u & 0x80000000u) ? (u & 0x7FFFFFFFu) : ~u;
    return __uint_as_float(b);
}
__device__ __forceinline__ unsigned short bf16rne(float f) {
    u32 u = __float_as_uint(f);
    u32 r = (u + 0x7FFFu + ((u >> 16) & 1u)) >> 16;
    return (unsigned short)r;
}
__device__ __forceinline__ float bflo(u32 u) { return __uint_as_float(u << 16); }
__device__ __forceinline__ float bfhi(u32 u) { return __uint_as_float(u & 0xFFFF0000u); }

// ---------- K_pq_hist: heterogeneous grid ----------
// blocks [0, nchunks): per-(chunk,bucket) histogram  gh[b*nchunks + c]
// blocks [nchunks, ..): per-node tables Pb = bf16(x@(W1a-W1b)+b1), Qb = bf16(x@W1b), packed 2/u32
__global__ __launch_bounds__(256) void k_pq_hist(
    const float* __restrict__ x, const float* __restrict__ W1, const float* __restrict__ b1,
    const int* __restrict__ ei,
    u32* __restrict__ Pb, u32* __restrict__ Qb, u32* __restrict__ gh,
    int N, int E, int NB, int nchunks)
{
    __shared__ float smem[4096];   // 16 KB, aliased by both roles

    if ((int)blockIdx.x < nchunks) {
        // ---- histogram role ----
        u32* cnt = (u32*)smem;     // [NB] (NB <= 4096 guaranteed by host)
        int c = blockIdx.x;
        for (int b = threadIdx.x; b < NB; b += 256) cnt[b] = 0;
        __syncthreads();
        int s0 = c * CH, end = min(E, s0 + CH);
        for (int e = s0 + threadIdx.x; e < end; e += 256) {
            int d = ei[E + e];
            atomicAdd(&cnt[d >> NPB_SHIFT], 1u);
        }
        __syncthreads();
        for (int b = threadIdx.x; b < NB; b += 256) gh[(size_t)b * nchunks + c] = cnt[b];
        return;
    }

    // ---- PQ role ----
    float* sWTa = smem;            // [j][k] = W1[k][j]-W1[k+32][j]
    float* sWTb = smem + 2048;     // [j][k] = W1[k+32][j]
    for (int idx = threadIdx.x; idx < 2048; idx += 256) {
        int j = idx >> 5, k = idx & 31;
        float a = W1[k * 64 + j];
        float b = W1[(k + 32) * 64 + j];
        sWTa[j * 32 + k] = a - b;
        sWTb[j * 32 + k] = b;
    }
    __syncthreads();

    int n = ((int)blockIdx.x - nchunks) * 256 + threadIdx.x;
    if (n >= N) return;
    float xr[32];
    const float4* x4 = reinterpret_cast<const float4*>(x + (size_t)n * 32);
#pragma unroll
    for (int q = 0; q < 8; ++q) {
        float4 v = x4[q];
        xr[4 * q] = v.x; xr[4 * q + 1] = v.y; xr[4 * q + 2] = v.z; xr[4 * q + 3] = v.w;
    }
    uint2* P2 = reinterpret_cast<uint2*>(Pb + (size_t)n * 32);
    uint2* Q2 = reinterpret_cast<uint2*>(Qb + (size_t)n * 32);
    for (int j0 = 0; j0 < 64; j0 += 4) {
        float pv[4], qv[4];
#pragma unroll
        for (int m = 0; m < 4; ++m) {
            int j = j0 + m;
            float a = b1[j], q = 0.f;
#pragma unroll
            for (int k = 0; k < 32; ++k) {
                a = fmaf(xr[k], sWTa[j * 32 + k], a);
                q = fmaf(xr[k], sWTb[j * 32 + k], q);
            }
            pv[m] = a; qv[m] = q;
        }
        P2[j0 >> 2] = make_uint2((u32)bf16rne(pv[0]) | ((u32)bf16rne(pv[1]) << 16),
                                 (u32)bf16rne(pv[2]) | ((u32)bf16rne(pv[3]) << 16));
        Q2[j0 >> 2] = make_uint2((u32)bf16rne(qv[0]) | ((u32)bf16rne(qv[1]) << 16),
                                 (u32)bf16rne(qv[2]) | ((u32)bf16rne(qv[3]) << 16));
    }
}

// ---------- exclusive scan, partial (1024/block) + block sums ----------
__global__ __launch_bounds__(256) void k_scan1(const u32* __restrict__ deg, u32* __restrict__ cursor,
                                               u32* __restrict__ bsum, int N) {
    __shared__ u32 sh[256];
    int t = threadIdx.x;
    int base = blockIdx.x * 1024 + t * 4;
    u32 v0 = 0, v1 = 0, v2 = 0, v3 = 0;
    if (base + 3 < N) {
        uint4 vv = *reinterpret_cast<const uint4*>(deg + base);
        v0 = vv.x; v1 = vv.y; v2 = vv.z; v3 = vv.w;
    } else {
        if (base < N) v0 = deg[base];
        if (base + 1 < N) v1 = deg[base + 1];
        if (base + 2 < N) v2 = deg[base + 2];
        if (base + 3 < N) v3 = deg[base + 3];
    }
    u32 s = v0 + v1 + v2 + v3;
    sh[t] = s; __syncthreads();
    u32 acc = s;
    for (int off = 1; off < 256; off <<= 1) {
        u32 add = (t >= off) ? sh[t - off] : 0;
        __syncthreads();
        acc += add; sh[t] = acc;
        __syncthreads();
    }
    u32 excl = acc - s;
    if (base < N) cursor[base] = excl;
    if (base + 1 < N) cursor[base + 1] = excl + v0;
    if (base + 2 < N) cursor[base + 2] = excl + v0 + v1;
    if (base + 3 < N) cursor[base + 3] = excl + v0 + v1 + v2;
    if (t == 255) bsum[blockIdx.x] = acc;
}

__global__ __launch_bounds__(256) void k_scan2(const u32* __restrict__ bsum, u32* __restrict__ bsumX, int nb) {
    __shared__ u32 sh[256];
    int t = threadIdx.x;
    u32 v = (t < nb) ? bsum[t] : 0;
    sh[t] = v; __syncthreads();
    u32 acc = v;
    for (int off = 1; off < 256; off <<= 1) {
        u32 add = (t >= off) ? sh[t - off] : 0;
        __syncthreads();
        acc += add; sh[t] = acc;
        __syncthreads();
    }
    if (t < nb) bsumX[t] = acc - v;
}

// ---------- K_scatter2: bucket edges, slot = (gcur+bsumX)[b][chunk] + LDS-rank ----------
// payload: src (17b) | local (5b) << 17
__global__ __launch_bounds__(256) void k_scatter2(const int* __restrict__ ei, const u32* __restrict__ gcur,
                                                  const u32* __restrict__ bsumX,
                                                  u32* __restrict__ sorted, int E, int NB, int nchunks) {
    extern __shared__ u32 sh[];    // [NB] base, [NB] cnt
    u32* base = sh;
    u32* cnt  = sh + NB;
    int c = blockIdx.x;
    for (int b = threadIdx.x; b < NB; b += 256) {
        size_t idx = (size_t)b * nchunks + c;
        base[b] = gcur[idx] + bsumX[idx >> 10];
        cnt[b] = 0;
    }
    __syncthreads();
    int s0 = c * CH, end = min(E, s0 + CH);
    for (int e = s0 + threadIdx.x; e < end; e += 256) {
        int d = ei[E + e];
        int s = ei[e];
        int b = d >> NPB_SHIFT;
        u32 r = atomicAdd(&cnt[b], 1u);
        sorted[base[b] + r] = (u32)s | ((u32)(d & (NPB - 1)) << 17);
    }
}

// ---------- K_bucket: one block per bucket; 2-stage pipelined gather + MFMA + LDS max-agg ----------
// A-frag (16x16x32 bf16): lane l holds A[row=l&15][k=(l>>4)*8 + j]
// C/D (m89-verified):     lane l, reg i -> D[row=(l>>4)*4+i][col=l&15]
// agg columns XOR-swizzled by row parity to spread LDS atomics across 32 banks
__global__ __launch_bounds__(256) void k_bucket(
    const u32* __restrict__ Pb, const u32* __restrict__ Qb,
    const u32* __restrict__ sorted, const u32* __restrict__ gcur,
    const u32* __restrict__ bsumX,
    const float* __restrict__ W2, const float* __restrict__ b2,
    float* __restrict__ out, int E, int N, int NB, int nchunks)
{
    __shared__ u32 agg[NPB * 32];   // 4 KB, encoded-u32 max, 0 = "untouched"
    int b = blockIdx.x;
    int tid = threadIdx.x;
    for (int i = tid; i < NPB * 32; i += 256) agg[i] = 0u;

    int lane = tid & 63;
    int wid = tid >> 6;
    int n = lane & 15;
    int kc = lane >> 4;

    // W2 resident as 4 bf16 B-fragments
    short8v b00, b01, b10, b11;
#pragma unroll
    for (int j = 0; j < 8; ++j) {
        int k = kc * 8 + j;
        b00[j] = (short)bf16rne(W2[k * 32 + n]);
        b01[j] = (short)bf16rne(W2[(k + 32) * 32 + n]);
        b10[j] = (short)bf16rne(W2[k * 32 + n + 16]);
        b11[j] = (short)bf16rne(W2[(k + 32) * 32 + n + 16]);
    }

    size_t i0 = (size_t)b * nchunks;
    u32 start = gcur[i0] + bsumX[i0 >> 10];
    u32 bend;
    if (b + 1 < NB) {
        size_t i1 = (size_t)(b + 1) * nchunks;
        bend = gcur[i1] + bsumX[i1 >> 10];
    } else {
        bend = (u32)E;
    }
    int ntiles = ((int)(bend - start) + 15) >> 4;
    int nodebase = b * NPB;

    __syncthreads();

    int t = wid;
    u32 slotA = start + (u32)t * 16u + (u32)n;
    u32 recA = 0;
    uint4 qA0, qA1, pA0, pA1;
    if (t < ntiles) {   // wave-uniform branch
        u32 sl = slotA < bend ? slotA : bend - 1;
        recA = sorted[sl];
        int src = (int)(recA & 0x1FFFFu);
        int loc = (int)(recA >> 17);
        const u32* qr = Qb + (size_t)src * 32;
        const u32* pr = Pb + (size_t)(nodebase + loc) * 32;
        qA0 = *(const uint4*)(qr + kc * 4);
        qA1 = *(const uint4*)(qr + 16 + kc * 4);
        pA0 = *(const uint4*)(pr + kc * 4);
        pA1 = *(const uint4*)(pr + 16 + kc * 4);
    }

    for (; t < ntiles; t += 4) {
        // ---- prefetch stage B (clamped-safe, may be garbage past the end) ----
        u32 slotB = start + (u32)(t + 4) * 16u + (u32)n;
        u32 slB = slotB < bend ? slotB : bend - 1;
        u32 recB = sorted[slB];
        int srcB = (int)(recB & 0x1FFFFu);
        int locB = (int)(recB >> 17);
        const u32* qrB = Qb + (size_t)srcB * 32;
        const u32* prB = Pb + (size_t)(nodebase + locB) * 32;
        uint4 qB0 = *(const uint4*)(qrB + kc * 4);
        uint4 qB1 = *(const uint4*)(qrB + 16 + kc * 4);
        uint4 pB0 = *(const uint4*)(prB + kc * 4);
        uint4 pB1 = *(const uint4*)(prB + 16 + kc * 4);

        // ---- compute stage A ----
        bool valid = slotA < bend;
        int local = valid ? (int)(recA >> 17) : -1;

        u32 pa[4] = {pA0.x, pA0.y, pA0.z, pA0.w};
        u32 ph[4] = {pA1.x, pA1.y, pA1.z, pA1.w};
        u32 qa[4] = {qA0.x, qA0.y, qA0.z, qA0.w};
        u32 qh[4] = {qA1.x, qA1.y, qA1.z, qA1.w};

        short8v a0, a1;
#pragma unroll
        for (int u = 0; u < 4; ++u) {
            a0[2 * u]     = (short)bf16rne(fmaxf(bflo(pa[u]) + bflo(qa[u]), 0.f));
            a0[2 * u + 1] = (short)bf16rne(fmaxf(bfhi(pa[u]) + bfhi(qa[u]), 0.f));
            a1[2 * u]     = (short)bf16rne(fmaxf(bflo(ph[u]) + bflo(qh[u]), 0.f));
            a1[2 * u + 1] = (short)bf16rne(fmaxf(bfhi(ph[u]) + bfhi(qh[u]), 0.f));
        }

        f32x4 d0 = {0.f, 0.f, 0.f, 0.f};
        f32x4 d1 = {0.f, 0.f, 0.f, 0.f};
        d0 = __builtin_amdgcn_mfma_f32_16x16x32_bf16(a0, b00, d0, 0, 0, 0);
        d0 = __builtin_amdgcn_mfma_f32_16x16x32_bf16(a1, b01, d0, 0, 0, 0);
        d1 = __builtin_amdgcn_mfma_f32_16x16x32_bf16(a0, b10, d1, 0, 0, 0);
        d1 = __builtin_amdgcn_mfma_f32_16x16x32_bf16(a1, b11, d1, 0, 0, 0);

        // rows owned by this lane: r = kc*4 + i; row r's record lives in lane r
#pragma unroll
        for (int i = 0; i < 4; ++i) {
            int r = kc * 4 + i;
            int lr = __shfl(local, r, 64);
            if (lr >= 0) {
                int sw = (lr & 1) << 4;
                atomicMax(&agg[(lr << 5) + (n ^ sw)], enc_f32(d0[i]));
                atomicMax(&agg[(lr << 5) + ((n + 16) ^ sw)], enc_f32(d1[i]));
            }
        }

        // ---- rotate ----
        slotA = slotB; recA = recB;
        qA0 = qB0; qA1 = qB1; pA0 = pB0; pA1 = pB1;
    }

    __syncthreads();
    // fused decode + b2 + empty->0; every node written exactly once
    for (int i = tid; i < NPB * 32; i += 256) {
        int local = i >> 5, c = i & 31;
        int node = nodebase + local;
        if (node < N) {
            u32 u = agg[(local << 5) + (c ^ ((local & 1) << 4))];
            out[(size_t)node * 32 + c] = u ? (dec_f32(u) + b2[c]) : 0.f;
        }
    }
}

// ---------- fallback (round-1 style) ----------
__global__ __launch_bounds__(256) void fb_edge(const float* __restrict__ x, const int* __restrict__ ei,
                                               const float* __restrict__ W1, const float* __restrict__ b1,
                                               const float* __restrict__ W2, const float* __restrict__ b2,
                                               u32* __restrict__ out, int E) {
    int e = blockIdx.x * 256 + threadIdx.x;
    if (e >= E) return;
    int src = ei[e], dst = ei[E + e];
    float m[64];
    const float4* xi4 = reinterpret_cast<const float4*>(x + (size_t)dst * 32);
    const float4* xj4 = reinterpret_cast<const float4*>(x + (size_t)src * 32);
#pragma unroll
    for (int q = 0; q < 8; ++q) {
        float4 a = xi4[q], b = xj4[q];
        m[q * 4] = a.x; m[q * 4 + 1] = a.y; m[q * 4 + 2] = a.z; m[q * 4 + 3] = a.w;
        m[32 + q * 4] = b.x - a.x; m[32 + q * 4 + 1] = b.y - a.y;
        m[32 + q * 4 + 2] = b.z - a.z; m[32 + q * 4 + 3] = b.w - a.w;
    }
    float acc[32];
#pragma unroll
    for (int c = 0; c < 32; ++c) acc[c] = b2[c];
    for (int j = 0; j < 64; ++j) {
        float h = b1[j];
#pragma unroll
        for (int k = 0; k < 64; ++k) h = fmaf(m[k], W1[k * 64 + j], h);
        h = fmaxf(h, 0.0f);
#pragma unroll
        for (int c = 0; c < 32; ++c) acc[c] = fmaf(h, W2[j * 32 + c], acc[c]);
    }
    u32* o = out + (size_t)dst * 32;
#pragma unroll
    for (int c = 0; c < 32; ++c) atomicMax(o + c, enc_f32(acc[c]));
}
__global__ __launch_bounds__(256) void fb_decode(u32* __restrict__ buf, int n) {
    int i = blockIdx.x * 256 + threadIdx.x;
    if (i >= n) return;
    u32 u = buf[i];
    reinterpret_cast<float*>(buf)[i] = u ? dec_f32(u) : 0.f;
}

extern "C" void kernel_launch(void* const* d_in, const int* in_sizes, int n_in,
                              void* d_out, int out_size, void* d_ws, size_t ws_size,
                              hipStream_t stream) {
    const float* x  = (const float*)d_in[0];
    const int*   ei = (const int*)d_in[1];
    const float* W1 = (const float*)d_in[2];
    const float* b1 = (const float*)d_in[3];
    const float* W2 = (const float*)d_in[4];
    const float* b2 = (const float*)d_in[5];

    int N = in_sizes[0] / 32;
    int E = in_sizes[1] / 2;
    int NB = (N + NPB - 1) / NPB;           // 3125 for N=100000
    int nchunks = (E + CH - 1) / CH;        // 49 for E=1.6M
    int M = NB * nchunks;                   // flat hist size (153125)

    // workspace layout (256B aligned)
    char* ws = (char*)d_ws;
    size_t off = 0;
    auto alloc = [&](size_t bytes) { char* p = ws + off; off += (bytes + 255) & ~(size_t)255; return p; };
    u32*   Pb     = (u32*)alloc((size_t)N * 32 * 4);
    u32*   Qb     = (u32*)alloc((size_t)N * 32 * 4);
    u32*   gh     = (u32*)alloc((size_t)M * 4);
    u32*   gcur   = (u32*)alloc((size_t)M * 4);
    u32*   bsum   = (u32*)alloc(256 * 4);
    u32*   bsumX  = (u32*)alloc(256 * 4);
    u32*   sorted = (u32*)alloc((size_t)E * 4);
    int nb = (M + 1023) / 1024;
    bool fits = (off <= ws_size) && (nb <= 256) && (N < (1 << 17));  // NB<=4096, src fits 17b

    if (!fits) {
        hipMemsetAsync(d_out, 0, (size_t)out_size * 4, stream);
        int be = (E + 255) / 256;
        fb_edge<<<be, 256, 0, stream>>>(x, ei, W1, b1, W2, b2, (u32*)d_out, E);
        fb_decode<<<(out_size + 255) / 256, 256, 0, stream>>>((u32*)d_out, out_size);
        return;
    }

    int pq_blocks = (N + 255) / 256;
    k_pq_hist<<<nchunks + pq_blocks, 256, 0, stream>>>(x, W1, b1, ei, Pb, Qb, gh, N, E, NB, nchunks);

    k_scan1<<<nb, 256, 0, stream>>>(gh, gcur, bsum, M);
    k_scan2<<<1, 256, 0, stream>>>(bsum, bsumX, nb);

    k_scatter2<<<nchunks, 256, (size_t)NB * 8, stream>>>(ei, gcur, bsumX, sorted, E, NB, nchunks);

    k_bucket<<<NB, 256, 0, stream>>>(Pb, Qb, sorted, gcur, bsumX, W2, b2, (float*)d_out, E, N, NB, nchunks);
}

// Round 7
// 157.329 us; speedup vs baseline: 13.4019x; 1.1400x over previous
//
#include <hip/hip_runtime.h>

typedef unsigned int u32;
typedef __attribute__((ext_vector_type(8))) short short8v;
typedef __attribute__((ext_vector_type(4))) float f32x4;

#define NPB 32           // nodes per bucket
#define NPB_SHIFT 5
#define CH  32768        // edges per chunk for hist/scatter

// order-preserving float<->uint encoding; enc never returns 0 for real values
__device__ __forceinline__ u32 enc_f32(float f) {
    u32 b = __float_as_uint(f);
    return (b & 0x80000000u) ? ~b : (b | 0x80000000u);
}
__device__ __forceinline__ float dec_f32(u32 u) {
    u32 b = (u & 0x80000000u) ? (u & 0x7FFFFFFFu) : ~u;
    return __uint_as_float(b);
}
__device__ __forceinline__ unsigned short bf16rne(float f) {
    u32 u = __float_as_uint(f);
    u32 r = (u + 0x7FFFu + ((u >> 16) & 1u)) >> 16;
    return (unsigned short)r;
}
__device__ __forceinline__ float bflo(u32 u) { return __uint_as_float(u << 16); }
__device__ __forceinline__ float bfhi(u32 u) { return __uint_as_float(u & 0xFFFF0000u); }

// ---------- K_pq_hist: heterogeneous grid ----------
// blocks [0, nchunks): per-(chunk,bucket) histogram  gh[b*nchunks + c]
// blocks [nchunks, ..): per-node tables Pb = bf16(x@(W1a-W1b)+b1), Qb = bf16(x@W1b)
// PQ writes go through a padded-LDS transpose so global stores are block-coalesced.
__global__ __launch_bounds__(256) void k_pq_hist(
    const float* __restrict__ x, const float* __restrict__ W1, const float* __restrict__ b1,
    const int* __restrict__ ei,
    u32* __restrict__ Pb, u32* __restrict__ Qb, u32* __restrict__ gh,
    int N, int E, int NB, int nchunks)
{
    __shared__ u32 smem[4224];     // 16.5 KB, aliased by all roles

    int tid = threadIdx.x;

    if ((int)blockIdx.x < nchunks) {
        // ---- histogram role (uint4 edge stream) ----
        u32* cnt = smem;           // [NB] (NB <= 4224 guaranteed by host)
        int c = blockIdx.x;
        for (int b = tid; b < NB; b += 256) cnt[b] = 0;
        __syncthreads();
        int s0 = c * CH, end = min(E, s0 + CH);
        int nquads = (end - s0) >> 2;           // host guarantees (end-s0)%4==0
        const int4* d4p = (const int4*)(ei + (size_t)E + s0);
        for (int qi = tid; qi < nquads; qi += 256) {
            int4 d4 = d4p[qi];
            atomicAdd(&cnt[d4.x >> NPB_SHIFT], 1u);
            atomicAdd(&cnt[d4.y >> NPB_SHIFT], 1u);
            atomicAdd(&cnt[d4.z >> NPB_SHIFT], 1u);
            atomicAdd(&cnt[d4.w >> NPB_SHIFT], 1u);
        }
        __syncthreads();
        for (int b = tid; b < NB; b += 256) gh[(size_t)b * nchunks + c] = cnt[b];
        return;
    }

    // ---- PQ role ----
    float* sWTa = (float*)smem;            // [j][k] = W1[k][j]-W1[k+32][j]  (words 0..2048)
    float* sWTb = (float*)smem + 2048;     // [j][k] = W1[k+32][j]           (words 2048..4096)
    for (int idx = tid; idx < 2048; idx += 256) {
        int j = idx >> 5, k = idx & 31;
        float a = W1[k * 64 + j];
        float b = W1[(k + 32) * 64 + j];
        sWTa[j * 32 + k] = a - b;
        sWTb[j * 32 + k] = b;
    }
    __syncthreads();

    int blk = (int)blockIdx.x - nchunks;
    int n = blk * 256 + tid;

    u32 pw[32], qw[32];
    if (n < N) {
        float xr[32];
        const float4* x4 = reinterpret_cast<const float4*>(x + (size_t)n * 32);
#pragma unroll
        for (int q = 0; q < 8; ++q) {
            float4 v = x4[q];
            xr[4 * q] = v.x; xr[4 * q + 1] = v.y; xr[4 * q + 2] = v.z; xr[4 * q + 3] = v.w;
        }
        for (int j0 = 0; j0 < 64; j0 += 4) {
            float pv[4], qv[4];
#pragma unroll
            for (int m = 0; m < 4; ++m) {
                int j = j0 + m;
                float a = b1[j], q = 0.f;
#pragma unroll
                for (int k = 0; k < 32; ++k) {
                    a = fmaf(xr[k], sWTa[j * 32 + k], a);
                    q = fmaf(xr[k], sWTb[j * 32 + k], q);
                }
                pv[m] = a; qv[m] = q;
            }
            pw[(j0 >> 1)]     = (u32)bf16rne(pv[0]) | ((u32)bf16rne(pv[1]) << 16);
            pw[(j0 >> 1) + 1] = (u32)bf16rne(pv[2]) | ((u32)bf16rne(pv[3]) << 16);
            qw[(j0 >> 1)]     = (u32)bf16rne(qv[0]) | ((u32)bf16rne(qv[1]) << 16);
            qw[(j0 >> 1) + 1] = (u32)bf16rne(qv[2]) | ((u32)bf16rne(qv[3]) << 16);
        }
    }
    __syncthreads();   // weights dead; smem re-used as staging

    // staging: 4 rounds of 64 rows; padded stride 33 kills bank conflicts
    u32* sP = smem;            // [64][33]
    u32* sQ = smem + 2112;     // [64][33]
    for (int r = 0; r < 4; ++r) {
        if ((tid >> 6) == r && n < N) {
            int row = tid & 63;
#pragma unroll
            for (int i = 0; i < 32; ++i) {
                sP[row * 33 + i] = pw[i];
                sQ[row * 33 + i] = qw[i];
            }
        }
        __syncthreads();
        int nodebase = blk * 256 + r * 64;
        size_t wbase = (size_t)nodebase * 32;
        for (int w = tid; w < 2048; w += 256) {
            int node = nodebase + (w >> 5);
            if (node < N) {
                u32 v = sP[(w >> 5) * 33 + (w & 31)];
                u32 u = sQ[(w >> 5) * 33 + (w & 31)];
                Pb[wbase + w] = v;
                Qb[wbase + w] = u;
            }
        }
        __syncthreads();
    }
}

// ---------- exclusive scan, partial (1024/block) + block sums ----------
__global__ __launch_bounds__(256) void k_scan1(const u32* __restrict__ deg, u32* __restrict__ cursor,
                                               u32* __restrict__ bsum, int N) {
    __shared__ u32 sh[256];
    int t = threadIdx.x;
    int base = blockIdx.x * 1024 + t * 4;
    u32 v0 = 0, v1 = 0, v2 = 0, v3 = 0;
    if (base + 3 < N) {
        uint4 vv = *reinterpret_cast<const uint4*>(deg + base);
        v0 = vv.x; v1 = vv.y; v2 = vv.z; v3 = vv.w;
    } else {
        if (base < N) v0 = deg[base];
        if (base + 1 < N) v1 = deg[base + 1];
        if (base + 2 < N) v2 = deg[base + 2];
        if (base + 3 < N) v3 = deg[base + 3];
    }
    u32 s = v0 + v1 + v2 + v3;
    sh[t] = s; __syncthreads();
    u32 acc = s;
    for (int off = 1; off < 256; off <<= 1) {
        u32 add = (t >= off) ? sh[t - off] : 0;
        __syncthreads();
        acc += add; sh[t] = acc;
        __syncthreads();
    }
    u32 excl = acc - s;
    if (base < N) cursor[base] = excl;
    if (base + 1 < N) cursor[base + 1] = excl + v0;
    if (base + 2 < N) cursor[base + 2] = excl + v0 + v1;
    if (base + 3 < N) cursor[base + 3] = excl + v0 + v1 + v2;
    if (t == 255) bsum[blockIdx.x] = acc;
}

__global__ __launch_bounds__(256) void k_scan2(const u32* __restrict__ bsum, u32* __restrict__ bsumX, int nb) {
    __shared__ u32 sh[256];
    int t = threadIdx.x;
    u32 v = (t < nb) ? bsum[t] : 0;
    sh[t] = v; __syncthreads();
    u32 acc = v;
    for (int off = 1; off < 256; off <<= 1) {
        u32 add = (t >= off) ? sh[t - off] : 0;
        __syncthreads();
        acc += add; sh[t] = acc;
        __syncthreads();
    }
    if (t < nb) bsumX[t] = acc - v;
}

// ---------- K_scatter2: bucket edges, slot = (gcur+bsumX)[b][chunk] + LDS-rank ----------
// payload: src (17b) | local (5b) << 17
__global__ __launch_bounds__(256) void k_scatter2(const int* __restrict__ ei, const u32* __restrict__ gcur,
                                                  const u32* __restrict__ bsumX,
                                                  u32* __restrict__ sorted, int E, int NB, int nchunks) {
    extern __shared__ u32 sh[];    // [NB] base, [NB] cnt
    u32* base = sh;
    u32* cnt  = sh + NB;
    int c = blockIdx.x;
    for (int b = threadIdx.x; b < NB; b += 256) {
        size_t idx = (size_t)b * nchunks + c;
        base[b] = gcur[idx] + bsumX[idx >> 10];
        cnt[b] = 0;
    }
    __syncthreads();
    int s0 = c * CH, end = min(E, s0 + CH);
    int nquads = (end - s0) >> 2;           // host guarantees (end-s0)%4==0
    const int4* d4p = (const int4*)(ei + (size_t)E + s0);
    const int4* s4p = (const int4*)(ei + s0);
    for (int qi = threadIdx.x; qi < nquads; qi += 256) {
        int4 d4 = d4p[qi];
        int4 s4 = s4p[qi];
        int dd[4] = {d4.x, d4.y, d4.z, d4.w};
        int ss[4] = {s4.x, s4.y, s4.z, s4.w};
#pragma unroll
        for (int u = 0; u < 4; ++u) {
            int b = dd[u] >> NPB_SHIFT;
            u32 r = atomicAdd(&cnt[b], 1u);
            sorted[base[b] + r] = (u32)ss[u] | ((u32)(dd[u] & (NPB - 1)) << 17);
        }
    }
}

// ---------- K_bucket: one block per bucket; 2-stage pipelined gather + MFMA + LDS max-agg ----------
// A-frag (16x16x32 bf16): lane l holds A[row=l&15][k=(l>>4)*8 + j]
// C/D (m89-verified):     lane l, reg i -> D[row=(l>>4)*4+i][col=l&15]
// agg columns XOR-swizzled by row parity to spread LDS atomics across 32 banks
__global__ __launch_bounds__(256) void k_bucket(
    const u32* __restrict__ Pb, const u32* __restrict__ Qb,
    const u32* __restrict__ sorted, const u32* __restrict__ gcur,
    const u32* __restrict__ bsumX,
    const float* __restrict__ W2, const float* __restrict__ b2,
    float* __restrict__ out, int E, int N, int NB, int nchunks)
{
    __shared__ u32 agg[NPB * 32];   // 4 KB, encoded-u32 max, 0 = "untouched"
    int b = blockIdx.x;
    int tid = threadIdx.x;
    for (int i = tid; i < NPB * 32; i += 256) agg[i] = 0u;

    int lane = tid & 63;
    int wid = tid >> 6;
    int n = lane & 15;
    int kc = lane >> 4;

    // W2 resident as 4 bf16 B-fragments
    short8v b00, b01, b10, b11;
#pragma unroll
    for (int j = 0; j < 8; ++j) {
        int k = kc * 8 + j;
        b00[j] = (short)bf16rne(W2[k * 32 + n]);
        b01[j] = (short)bf16rne(W2[(k + 32) * 32 + n]);
        b10[j] = (short)bf16rne(W2[k * 32 + n + 16]);
        b11[j] = (short)bf16rne(W2[(k + 32) * 32 + n + 16]);
    }

    size_t i0 = (size_t)b * nchunks;
    u32 start = gcur[i0] + bsumX[i0 >> 10];
    u32 bend;
    if (b + 1 < NB) {
        size_t i1 = (size_t)(b + 1) * nchunks;
        bend = gcur[i1] + bsumX[i1 >> 10];
    } else {
        bend = (u32)E;
    }
    int ntiles = ((int)(bend - start) + 15) >> 4;
    int nodebase = b * NPB;

    __syncthreads();

    int t = wid;
    u32 slotA = start + (u32)t * 16u + (u32)n;
    u32 recA = 0;
    uint4 qA0, qA1, pA0, pA1;
    if (t < ntiles) {   // wave-uniform branch
        u32 sl = slotA < bend ? slotA : bend - 1;
        recA = sorted[sl];
        int src = (int)(recA & 0x1FFFFu);
        int loc = (int)(recA >> 17);
        const u32* qr = Qb + (size_t)src * 32;
        const u32* pr = Pb + (size_t)(nodebase + loc) * 32;
        qA0 = *(const uint4*)(qr + kc * 4);
        qA1 = *(const uint4*)(qr + 16 + kc * 4);
        pA0 = *(const uint4*)(pr + kc * 4);
        pA1 = *(const uint4*)(pr + 16 + kc * 4);
    }

    for (; t < ntiles; t += 4) {
        // ---- prefetch stage B (clamped-safe, may be garbage past the end) ----
        u32 slotB = start + (u32)(t + 4) * 16u + (u32)n;
        u32 slB = slotB < bend ? slotB : bend - 1;
        u32 recB = sorted[slB];
        int srcB = (int)(recB & 0x1FFFFu);
        int locB = (int)(recB >> 17);
        const u32* qrB = Qb + (size_t)srcB * 32;
        const u32* prB = Pb + (size_t)(nodebase + locB) * 32;
        uint4 qB0 = *(const uint4*)(qrB + kc * 4);
        uint4 qB1 = *(const uint4*)(qrB + 16 + kc * 4);
        uint4 pB0 = *(const uint4*)(prB + kc * 4);
        uint4 pB1 = *(const uint4*)(prB + 16 + kc * 4);

        // ---- compute stage A ----
        bool valid = slotA < bend;
        int local = valid ? (int)(recA >> 17) : -1;

        u32 pa[4] = {pA0.x, pA0.y, pA0.z, pA0.w};
        u32 ph[4] = {pA1.x, pA1.y, pA1.z, pA1.w};
        u32 qa[4] = {qA0.x, qA0.y, qA0.z, qA0.w};
        u32 qh[4] = {qA1.x, qA1.y, qA1.z, qA1.w};

        short8v a0, a1;
#pragma unroll
        for (int u = 0; u < 4; ++u) {
            a0[2 * u]     = (short)bf16rne(fmaxf(bflo(pa[u]) + bflo(qa[u]), 0.f));
            a0[2 * u + 1] = (short)bf16rne(fmaxf(bfhi(pa[u]) + bfhi(qa[u]), 0.f));
            a1[2 * u]     = (short)bf16rne(fmaxf(bflo(ph[u]) + bflo(qh[u]), 0.f));
            a1[2 * u + 1] = (short)bf16rne(fmaxf(bfhi(ph[u]) + bfhi(qh[u]), 0.f));
        }

        f32x4 d0 = {0.f, 0.f, 0.f, 0.f};
        f32x4 d1 = {0.f, 0.f, 0.f, 0.f};
        d0 = __builtin_amdgcn_mfma_f32_16x16x32_bf16(a0, b00, d0, 0, 0, 0);
        d0 = __builtin_amdgcn_mfma_f32_16x16x32_bf16(a1, b01, d0, 0, 0, 0);
        d1 = __builtin_amdgcn_mfma_f32_16x16x32_bf16(a0, b10, d1, 0, 0, 0);
        d1 = __builtin_amdgcn_mfma_f32_16x16x32_bf16(a1, b11, d1, 0, 0, 0);

        // rows owned by this lane: r = kc*4 + i; row r's record lives in lane r
#pragma unroll
        for (int i = 0; i < 4; ++i) {
            int r = kc * 4 + i;
            int lr = __shfl(local, r, 64);
            if (lr >= 0) {
                int sw = (lr & 1) << 4;
                atomicMax(&agg[(lr << 5) + (n ^ sw)], enc_f32(d0[i]));
                atomicMax(&agg[(lr << 5) + ((n + 16) ^ sw)], enc_f32(d1[i]));
            }
        }

        // ---- rotate ----
        slotA = slotB; recA = recB;
        qA0 = qB0; qA1 = qB1; pA0 = pB0; pA1 = pB1;
    }

    __syncthreads();
    // fused decode + b2 + empty->0; every node written exactly once
    for (int i = tid; i < NPB * 32; i += 256) {
        int local = i >> 5, c = i & 31;
        int node = nodebase + local;
        if (node < N) {
            u32 u = agg[(local << 5) + (c ^ ((local & 1) << 4))];
            out[(size_t)node * 32 + c] = u ? (dec_f32(u) + b2[c]) : 0.f;
        }
    }
}

// ---------- fallback (round-1 style) ----------
__global__ __launch_bounds__(256) void fb_edge(const float* __restrict__ x, const int* __restrict__ ei,
                                               const float* __restrict__ W1, const float* __restrict__ b1,
                                               const float* __restrict__ W2, const float* __restrict__ b2,
                                               u32* __restrict__ out, int E) {
    int e = blockIdx.x * 256 + threadIdx.x;
    if (e >= E) return;
    int src = ei[e], dst = ei[E + e];
    float m[64];
    const float4* xi4 = reinterpret_cast<const float4*>(x + (size_t)dst * 32);
    const float4* xj4 = reinterpret_cast<const float4*>(x + (size_t)src * 32);
#pragma unroll
    for (int q = 0; q < 8; ++q) {
        float4 a = xi4[q], b = xj4[q];
        m[q * 4] = a.x; m[q * 4 + 1] = a.y; m[q * 4 + 2] = a.z; m[q * 4 + 3] = a.w;
        m[32 + q * 4] = b.x - a.x; m[32 + q * 4 + 1] = b.y - a.y;
        m[32 + q * 4 + 2] = b.z - a.z; m[32 + q * 4 + 3] = b.w - a.w;
    }
    float acc[32];
#pragma unroll
    for (int c = 0; c < 32; ++c) acc[c] = b2[c];
    for (int j = 0; j < 64; ++j) {
        float h = b1[j];
#pragma unroll
        for (int k = 0; k < 64; ++k) h = fmaf(m[k], W1[k * 64 + j], h);
        h = fmaxf(h, 0.0f);
#pragma unroll
        for (int c = 0; c < 32; ++c) acc[c] = fmaf(h, W2[j * 32 + c], acc[c]);
    }
    u32* o = out + (size_t)dst * 32;
#pragma unroll
    for (int c = 0; c < 32; ++c) atomicMax(o + c, enc_f32(acc[c]));
}
__global__ __launch_bounds__(256) void fb_decode(u32* __restrict__ buf, int n) {
    int i = blockIdx.x * 256 + threadIdx.x;
    if (i >= n) return;
    u32 u = buf[i];
    reinterpret_cast<float*>(buf)[i] = u ? dec_f32(u) : 0.f;
}

extern "C" void kernel_launch(void* const* d_in, const int* in_sizes, int n_in,
                              void* d_out, int out_size, void* d_ws, size_t ws_size,
                              hipStream_t stream) {
    const float* x  = (const float*)d_in[0];
    const int*   ei = (const int*)d_in[1];
    const float* W1 = (const float*)d_in[2];
    const float* b1 = (const float*)d_in[3];
    const float* W2 = (const float*)d_in[4];
    const float* b2 = (const float*)d_in[5];

    int N = in_sizes[0] / 32;
    int E = in_sizes[1] / 2;
    int NB = (N + NPB - 1) / NPB;           // 3125 for N=100000
    int nchunks = (E + CH - 1) / CH;        // 49 for E=1.6M
    int M = NB * nchunks;                   // flat hist size (153125)

    // workspace layout (256B aligned)
    char* ws = (char*)d_ws;
    size_t off = 0;
    auto alloc = [&](size_t bytes) { char* p = ws + off; off += (bytes + 255) & ~(size_t)255; return p; };
    u32*   Pb     = (u32*)alloc((size_t)N * 32 * 4);
    u32*   Qb     = (u32*)alloc((size_t)N * 32 * 4);
    u32*   gh     = (u32*)alloc((size_t)M * 4);
    u32*   gcur   = (u32*)alloc((size_t)M * 4);
    u32*   bsum   = (u32*)alloc(256 * 4);
    u32*   bsumX  = (u32*)alloc(256 * 4);
    u32*   sorted = (u32*)alloc((size_t)E * 4);
    int nb = (M + 1023) / 1024;
    // NB<=4224 (hist LDS), src fits 17b, E%4 for uint4 edge streams
    bool fits = (off <= ws_size) && (nb <= 256) && (N < (1 << 17)) && ((E & 3) == 0);

    if (!fits) {
        hipMemsetAsync(d_out, 0, (size_t)out_size * 4, stream);
        int be = (E + 255) / 256;
        fb_edge<<<be, 256, 0, stream>>>(x, ei, W1, b1, W2, b2, (u32*)d_out, E);
        fb_decode<<<(out_size + 255) / 256, 256, 0, stream>>>((u32*)d_out, out_size);
        return;
    }

    int pq_blocks = (N + 255) / 256;
    k_pq_hist<<<nchunks + pq_blocks, 256, 0, stream>>>(x, W1, b1, ei, Pb, Qb, gh, N, E, NB, nchunks);

    k_scan1<<<nb, 256, 0, stream>>>(gh, gcur, bsum, M);
    k_scan2<<<1, 256, 0, stream>>>(bsum, bsumX, nb);

    k_scatter2<<<nchunks, 256, (size_t)NB * 8, stream>>>(ei, gcur, bsumX, sorted, E, NB, nchunks);

    k_bucket<<<NB, 256, 0, stream>>>(Pb, Qb, sorted, gcur, bsumX, W2, b2, (float*)d_out, E, N, NB, nchunks);
}

// Round 8
// 156.682 us; speedup vs baseline: 13.4573x; 1.0041x over previous
//
#include <hip/hip_runtime.h>

typedef unsigned int u32;
typedef __attribute__((ext_vector_type(8))) short short8v;
typedef __attribute__((ext_vector_type(4))) float f32x4;

#define NPB 32           // nodes per bucket
#define NPB_SHIFT 5
#define CH2 4096         // edges per scatter block
#define HB  64           // histogram blocks

// order-preserving float<->uint encoding; enc never returns 0 for real values
__device__ __forceinline__ u32 enc_f32(float f) {
    u32 b = __float_as_uint(f);
    return (b & 0x80000000u) ? ~b : (b | 0x80000000u);
}
__device__ __forceinline__ float dec_f32(u32 u) {
    u32 b = (u & 0x80000000u) ? (u & 0x7FFFFFFFu) : ~u;
    return __uint_as_float(b);
}
__device__ __forceinline__ unsigned short bf16rne(float f) {
    u32 u = __float_as_uint(f);
    u32 r = (u + 0x7FFFu + ((u >> 16) & 1u)) >> 16;
    return (unsigned short)r;
}
__device__ __forceinline__ float bflo(u32 u) { return __uint_as_float(u << 16); }
__device__ __forceinline__ float bfhi(u32 u) { return __uint_as_float(u & 0xFFFF0000u); }

// ---------- K_pq_hist: heterogeneous grid ----------
// blocks [0, HB): LDS-aggregated bucket histogram -> global atomicAdd deg[b]
// blocks [HB, ..): per-node tables Pb = bf16(x@(W1a-W1b)+b1), Qb = bf16(x@W1b)
__global__ __launch_bounds__(256) void k_pq_hist(
    const float* __restrict__ x, const float* __restrict__ W1, const float* __restrict__ b1,
    const int* __restrict__ ei,
    u32* __restrict__ Pb, u32* __restrict__ Qb, u32* __restrict__ deg,
    int N, int E, int NB)
{
    __shared__ u32 smem[4224];     // 16.5 KB, aliased by all roles
    int tid = threadIdx.x;

    if ((int)blockIdx.x < HB) {
        // ---- histogram role: grid-stride over edge quads ----
        u32* cnt = smem;           // [NB]
        for (int b = tid; b < NB; b += 256) cnt[b] = 0;
        __syncthreads();
        int nquads = E >> 2;       // host guarantees E%4==0
        const int4* d4p = (const int4*)(ei + (size_t)E);
        for (int qi = (int)blockIdx.x * 256 + tid; qi < nquads; qi += HB * 256) {
            int4 d4 = d4p[qi];
            atomicAdd(&cnt[d4.x >> NPB_SHIFT], 1u);
            atomicAdd(&cnt[d4.y >> NPB_SHIFT], 1u);
            atomicAdd(&cnt[d4.z >> NPB_SHIFT], 1u);
            atomicAdd(&cnt[d4.w >> NPB_SHIFT], 1u);
        }
        __syncthreads();
        for (int b = tid; b < NB; b += 256)
            if (cnt[b]) atomicAdd(&deg[b], cnt[b]);
        return;
    }

    // ---- PQ role ----
    float* sWTa = (float*)smem;            // [j][k] = W1[k][j]-W1[k+32][j]
    float* sWTb = (float*)smem + 2048;     // [j][k] = W1[k+32][j]
    for (int idx = tid; idx < 2048; idx += 256) {
        int j = idx >> 5, k = idx & 31;
        float a = W1[k * 64 + j];
        float b = W1[(k + 32) * 64 + j];
        sWTa[j * 32 + k] = a - b;
        sWTb[j * 32 + k] = b;
    }
    __syncthreads();

    int blk = (int)blockIdx.x - HB;
    int n = blk * 256 + tid;

    u32 pw[32], qw[32];
    if (n < N) {
        float xr[32];
        const float4* x4 = reinterpret_cast<const float4*>(x + (size_t)n * 32);
#pragma unroll
        for (int q = 0; q < 8; ++q) {
            float4 v = x4[q];
            xr[4 * q] = v.x; xr[4 * q + 1] = v.y; xr[4 * q + 2] = v.z; xr[4 * q + 3] = v.w;
        }
        for (int j0 = 0; j0 < 64; j0 += 4) {
            float pv[4], qv[4];
#pragma unroll
            for (int m = 0; m < 4; ++m) {
                int j = j0 + m;
                float a = b1[j], q = 0.f;
#pragma unroll
                for (int k = 0; k < 32; ++k) {
                    a = fmaf(xr[k], sWTa[j * 32 + k], a);
                    q = fmaf(xr[k], sWTb[j * 32 + k], q);
                }
                pv[m] = a; qv[m] = q;
            }
            pw[(j0 >> 1)]     = (u32)bf16rne(pv[0]) | ((u32)bf16rne(pv[1]) << 16);
            pw[(j0 >> 1) + 1] = (u32)bf16rne(pv[2]) | ((u32)bf16rne(pv[3]) << 16);
            qw[(j0 >> 1)]     = (u32)bf16rne(qv[0]) | ((u32)bf16rne(qv[1]) << 16);
            qw[(j0 >> 1) + 1] = (u32)bf16rne(qv[2]) | ((u32)bf16rne(qv[3]) << 16);
        }
    }
    __syncthreads();   // weights dead; smem re-used as staging

    // staging: 4 rounds of 64 rows; padded stride 33 kills bank conflicts
    u32* sP = smem;            // [64][33]
    u32* sQ = smem + 2112;     // [64][33]
    for (int r = 0; r < 4; ++r) {
        if ((tid >> 6) == r && n < N) {
            int row = tid & 63;
#pragma unroll
            for (int i = 0; i < 32; ++i) {
                sP[row * 33 + i] = pw[i];
                sQ[row * 33 + i] = qw[i];
            }
        }
        __syncthreads();
        int nodebase = blk * 256 + r * 64;
        size_t wbase = (size_t)nodebase * 32;
        for (int w = tid; w < 2048; w += 256) {
            int node = nodebase + (w >> 5);
            if (node < N) {
                u32 v = sP[(w >> 5) * 33 + (w & 31)];
                u32 u = sQ[(w >> 5) * 33 + (w & 31)];
                Pb[wbase + w] = v;
                Qb[wbase + w] = u;
            }
        }
        __syncthreads();
    }
}

// ---------- K_scan: single block, exclusive scan of deg[NB] -> base[NB+1], cursor copy ----------
__global__ __launch_bounds__(256) void k_scan(const u32* __restrict__ deg,
                                              u32* __restrict__ base, u32* __restrict__ cursor, int NB) {
    __shared__ u32 sh[256];
    __shared__ u32 carry;
    int t = threadIdx.x;
    if (t == 0) carry = 0;
    __syncthreads();
    for (int r0 = 0; r0 < NB; r0 += 256) {
        int i = r0 + t;
        u32 v = (i < NB) ? deg[i] : 0;
        sh[t] = v; __syncthreads();
        u32 acc = v;
        for (int off = 1; off < 256; off <<= 1) {
            u32 add = (t >= off) ? sh[t - off] : 0;
            __syncthreads();
            acc += add; sh[t] = acc;
            __syncthreads();
        }
        u32 excl = carry + acc - v;
        if (i < NB) { base[i] = excl; cursor[i] = excl; }
        __syncthreads();
        if (t == 255) carry += acc;
        __syncthreads();
    }
    if (t == 0) base[NB] = carry;
}

// ---------- K_scatter3: two-pass LDS bucket scatter with atomic-cursor allocation ----------
// payload: src (17b) | local (5b) << 17   (order within bucket is arbitrary; max is commutative)
__global__ __launch_bounds__(256) void k_scatter3(const int* __restrict__ ei,
                                                  u32* __restrict__ cursor,
                                                  u32* __restrict__ sorted, int E, int NB) {
    extern __shared__ u32 sh[];    // [NB] cnt, [NB] sbase
    u32* cnt   = sh;
    u32* sbase = sh + NB;
    int tid = threadIdx.x;
    for (int b = tid; b < NB; b += 256) cnt[b] = 0;
    __syncthreads();

    int s0 = (int)blockIdx.x * CH2, end = min(E, s0 + CH2);
    int nquads = (end - s0) >> 2;          // host guarantees multiples of 4
    const int4* d4p = (const int4*)(ei + (size_t)E + s0);
    const int4* s4p = (const int4*)(ei + s0);

    // pass A: count
    for (int qi = tid; qi < nquads; qi += 256) {
        int4 d4 = d4p[qi];
        atomicAdd(&cnt[d4.x >> NPB_SHIFT], 1u);
        atomicAdd(&cnt[d4.y >> NPB_SHIFT], 1u);
        atomicAdd(&cnt[d4.z >> NPB_SHIFT], 1u);
        atomicAdd(&cnt[d4.w >> NPB_SHIFT], 1u);
    }
    __syncthreads();

    // allocate contiguous ranges; reset cnt for rank pass
    for (int b = tid; b < NB; b += 256) {
        u32 c = cnt[b];
        if (c) sbase[b] = atomicAdd(&cursor[b], c);
        cnt[b] = 0;
    }
    __syncthreads();

    // pass B: place
    for (int qi = tid; qi < nquads; qi += 256) {
        int4 d4 = d4p[qi];
        int4 s4 = s4p[qi];
        int dd[4] = {d4.x, d4.y, d4.z, d4.w};
        int ss[4] = {s4.x, s4.y, s4.z, s4.w};
#pragma unroll
        for (int u = 0; u < 4; ++u) {
            int b = dd[u] >> NPB_SHIFT;
            u32 r = atomicAdd(&cnt[b], 1u);
            sorted[sbase[b] + r] = (u32)ss[u] | ((u32)(dd[u] & (NPB - 1)) << 17);
        }
    }
}

// ---------- K_bucket: one block per bucket; 2-stage pipelined gather + MFMA + LDS max-agg ----------
// A-frag (16x16x32 bf16): lane l holds A[row=l&15][k=(l>>4)*8 + j]
// C/D (m89-verified):     lane l, reg i -> D[row=(l>>4)*4+i][col=l&15]
// agg columns XOR-swizzled by row parity to spread LDS atomics across 32 banks
__global__ __launch_bounds__(256) void k_bucket(
    const u32* __restrict__ Pb, const u32* __restrict__ Qb,
    const u32* __restrict__ sorted, const u32* __restrict__ base,
    const float* __restrict__ W2, const float* __restrict__ b2,
    float* __restrict__ out, int N, int NB)
{
    __shared__ u32 agg[NPB * 32];   // 4 KB, encoded-u32 max, 0 = "untouched"
    int b = blockIdx.x;
    int tid = threadIdx.x;
    for (int i = tid; i < NPB * 32; i += 256) agg[i] = 0u;

    int lane = tid & 63;
    int wid = tid >> 6;
    int n = lane & 15;
    int kc = lane >> 4;

    // W2 resident as 4 bf16 B-fragments
    short8v b00, b01, b10, b11;
#pragma unroll
    for (int j = 0; j < 8; ++j) {
        int k = kc * 8 + j;
        b00[j] = (short)bf16rne(W2[k * 32 + n]);
        b01[j] = (short)bf16rne(W2[(k + 32) * 32 + n]);
        b10[j] = (short)bf16rne(W2[k * 32 + n + 16]);
        b11[j] = (short)bf16rne(W2[(k + 32) * 32 + n + 16]);
    }

    u32 start = base[b];
    u32 bend  = base[b + 1];
    int ntiles = ((int)(bend - start) + 15) >> 4;
    int nodebase = b * NPB;

    __syncthreads();

    int t = wid;
    u32 slotA = start + (u32)t * 16u + (u32)n;
    u32 recA = 0;
    uint4 qA0, qA1, pA0, pA1;
    if (t < ntiles) {   // wave-uniform branch
        u32 sl = slotA < bend ? slotA : bend - 1;
        recA = sorted[sl];
        int src = (int)(recA & 0x1FFFFu);
        int loc = (int)(recA >> 17);
        const u32* qr = Qb + (size_t)src * 32;
        const u32* pr = Pb + (size_t)(nodebase + loc) * 32;
        qA0 = *(const uint4*)(qr + kc * 4);
        qA1 = *(const uint4*)(qr + 16 + kc * 4);
        pA0 = *(const uint4*)(pr + kc * 4);
        pA1 = *(const uint4*)(pr + 16 + kc * 4);
    }

    for (; t < ntiles; t += 4) {
        // ---- prefetch stage B (clamped-safe) ----
        u32 slotB = start + (u32)(t + 4) * 16u + (u32)n;
        u32 slB = slotB < bend ? slotB : bend - 1;
        u32 recB = sorted[slB];
        int srcB = (int)(recB & 0x1FFFFu);
        int locB = (int)(recB >> 17);
        const u32* qrB = Qb + (size_t)srcB * 32;
        const u32* prB = Pb + (size_t)(nodebase + locB) * 32;
        uint4 qB0 = *(const uint4*)(qrB + kc * 4);
        uint4 qB1 = *(const uint4*)(qrB + 16 + kc * 4);
        uint4 pB0 = *(const uint4*)(prB + kc * 4);
        uint4 pB1 = *(const uint4*)(prB + 16 + kc * 4);

        // ---- compute stage A ----
        bool valid = slotA < bend;
        int local = valid ? (int)(recA >> 17) : -1;

        u32 pa[4] = {pA0.x, pA0.y, pA0.z, pA0.w};
        u32 ph[4] = {pA1.x, pA1.y, pA1.z, pA1.w};
        u32 qa[4] = {qA0.x, qA0.y, qA0.z, qA0.w};
        u32 qh[4] = {qA1.x, qA1.y, qA1.z, qA1.w};

        short8v a0, a1;
#pragma unroll
        for (int u = 0; u < 4; ++u) {
            a0[2 * u]     = (short)bf16rne(fmaxf(bflo(pa[u]) + bflo(qa[u]), 0.f));
            a0[2 * u + 1] = (short)bf16rne(fmaxf(bfhi(pa[u]) + bfhi(qa[u]), 0.f));
            a1[2 * u]     = (short)bf16rne(fmaxf(bflo(ph[u]) + bflo(qh[u]), 0.f));
            a1[2 * u + 1] = (short)bf16rne(fmaxf(bfhi(ph[u]) + bfhi(qh[u]), 0.f));
        }

        f32x4 d0 = {0.f, 0.f, 0.f, 0.f};
        f32x4 d1 = {0.f, 0.f, 0.f, 0.f};
        d0 = __builtin_amdgcn_mfma_f32_16x16x32_bf16(a0, b00, d0, 0, 0, 0);
        d0 = __builtin_amdgcn_mfma_f32_16x16x32_bf16(a1, b01, d0, 0, 0, 0);
        d1 = __builtin_amdgcn_mfma_f32_16x16x32_bf16(a0, b10, d1, 0, 0, 0);
        d1 = __builtin_amdgcn_mfma_f32_16x16x32_bf16(a1, b11, d1, 0, 0, 0);

        // rows owned by this lane: r = kc*4 + i; row r's record lives in lane r
#pragma unroll
        for (int i = 0; i < 4; ++i) {
            int r = kc * 4 + i;
            int lr = __shfl(local, r, 64);
            if (lr >= 0) {
                int sw = (lr & 1) << 4;
                atomicMax(&agg[(lr << 5) + (n ^ sw)], enc_f32(d0[i]));
                atomicMax(&agg[(lr << 5) + ((n + 16) ^ sw)], enc_f32(d1[i]));
            }
        }

        // ---- rotate ----
        slotA = slotB; recA = recB;
        qA0 = qB0; qA1 = qB1; pA0 = pB0; pA1 = pB1;
    }

    __syncthreads();
    // fused decode + b2 + empty->0; every node written exactly once
    for (int i = tid; i < NPB * 32; i += 256) {
        int local = i >> 5, c = i & 31;
        int node = nodebase + local;
        if (node < N) {
            u32 u = agg[(local << 5) + (c ^ ((local & 1) << 4))];
            out[(size_t)node * 32 + c] = u ? (dec_f32(u) + b2[c]) : 0.f;
        }
    }
}

// ---------- fallback (round-1 style) ----------
__global__ __launch_bounds__(256) void fb_edge(const float* __restrict__ x, const int* __restrict__ ei,
                                               const float* __restrict__ W1, const float* __restrict__ b1,
                                               const float* __restrict__ W2, const float* __restrict__ b2,
                                               u32* __restrict__ out, int E) {
    int e = blockIdx.x * 256 + threadIdx.x;
    if (e >= E) return;
    int src = ei[e], dst = ei[E + e];
    float m[64];
    const float4* xi4 = reinterpret_cast<const float4*>(x + (size_t)dst * 32);
    const float4* xj4 = reinterpret_cast<const float4*>(x + (size_t)src * 32);
#pragma unroll
    for (int q = 0; q < 8; ++q) {
        float4 a = xi4[q], b = xj4[q];
        m[q * 4] = a.x; m[q * 4 + 1] = a.y; m[q * 4 + 2] = a.z; m[q * 4 + 3] = a.w;
        m[32 + q * 4] = b.x - a.x; m[32 + q * 4 + 1] = b.y - a.y;
        m[32 + q * 4 + 2] = b.z - a.z; m[32 + q * 4 + 3] = b.w - a.w;
    }
    float acc[32];
#pragma unroll
    for (int c = 0; c < 32; ++c) acc[c] = b2[c];
    for (int j = 0; j < 64; ++j) {
        float h = b1[j];
#pragma unroll
        for (int k = 0; k < 64; ++k) h = fmaf(m[k], W1[k * 64 + j], h);
        h = fmaxf(h, 0.0f);
#pragma unroll
        for (int c = 0; c < 32; ++c) acc[c] = fmaf(h, W2[j * 32 + c], acc[c]);
    }
    u32* o = out + (size_t)dst * 32;
#pragma unroll
    for (int c = 0; c < 32; ++c) atomicMax(o + c, enc_f32(acc[c]));
}
__global__ __launch_bounds__(256) void fb_decode(u32* __restrict__ buf, int n) {
    int i = blockIdx.x * 256 + threadIdx.x;
    if (i >= n) return;
    u32 u = buf[i];
    reinterpret_cast<float*>(buf)[i] = u ? dec_f32(u) : 0.f;
}

extern "C" void kernel_launch(void* const* d_in, const int* in_sizes, int n_in,
                              void* d_out, int out_size, void* d_ws, size_t ws_size,
                              hipStream_t stream) {
    const float* x  = (const float*)d_in[0];
    const int*   ei = (const int*)d_in[1];
    const float* W1 = (const float*)d_in[2];
    const float* b1 = (const float*)d_in[3];
    const float* W2 = (const float*)d_in[4];
    const float* b2 = (const float*)d_in[5];

    int N = in_sizes[0] / 32;
    int E = in_sizes[1] / 2;
    int NB = (N + NPB - 1) / NPB;           // 3125 for N=100000
    int nsc = (E + CH2 - 1) / CH2;          // 391 scatter blocks for E=1.6M

    // workspace layout (256B aligned)
    char* ws = (char*)d_ws;
    size_t off = 0;
    auto alloc = [&](size_t bytes) { char* p = ws + off; off += (bytes + 255) & ~(size_t)255; return p; };
    u32*   Pb     = (u32*)alloc((size_t)N * 32 * 4);
    u32*   Qb     = (u32*)alloc((size_t)N * 32 * 4);
    u32*   deg    = (u32*)alloc((size_t)NB * 4);
    u32*   base   = (u32*)alloc((size_t)(NB + 1) * 4);
    u32*   cursor = (u32*)alloc((size_t)NB * 4);
    u32*   sorted = (u32*)alloc((size_t)E * 4);
    // NB<=4224 (hist LDS), src fits 17b, E%4 for uint4 edge streams
    bool fits = (off <= ws_size) && (NB <= 4224) && (N < (1 << 17)) && ((E & 3) == 0);

    if (!fits) {
        hipMemsetAsync(d_out, 0, (size_t)out_size * 4, stream);
        int be = (E + 255) / 256;
        fb_edge<<<be, 256, 0, stream>>>(x, ei, W1, b1, W2, b2, (u32*)d_out, E);
        fb_decode<<<(out_size + 255) / 256, 256, 0, stream>>>((u32*)d_out, out_size);
        return;
    }

    hipMemsetAsync(deg, 0, (size_t)NB * 4, stream);

    int pq_blocks = (N + 255) / 256;
    k_pq_hist<<<HB + pq_blocks, 256, 0, stream>>>(x, W1, b1, ei, Pb, Qb, deg, N, E, NB);

    k_scan<<<1, 256, 0, stream>>>(deg, base, cursor, NB);

    k_scatter3<<<nsc, 256, (size_t)NB * 8, stream>>>(ei, cursor, sorted, E, NB);

    k_bucket<<<NB, 256, 0, stream>>>(Pb, Qb, sorted, base, W2, b2, (float*)d_out, N, NB);
}

// Round 9
// 155.803 us; speedup vs baseline: 13.5332x; 1.0056x over previous
//
#include <hip/hip_runtime.h>

typedef unsigned int u32;
typedef __attribute__((ext_vector_type(8))) short short8v;
typedef __attribute__((ext_vector_type(4))) u32 u32x4;
typedef __attribute__((ext_vector_type(4))) float f32x4;

#define NPB 32           // nodes per fine bucket
#define NPB_SHIFT 5
#define SB_SHIFT 11      // coarse bucket = 2048 nodes
#define CHP 4096         // edges per scatter-phase block
#define HB  64           // fine-hist blocks

// order-preserving float<->uint encoding; enc never returns 0 for real values
__device__ __forceinline__ u32 enc_f32(float f) {
    u32 b = __float_as_uint(f);
    return (b & 0x80000000u) ? ~b : (b | 0x80000000u);
}
__device__ __forceinline__ float dec_f32(u32 u) {
    u32 b = (u & 0x80000000u) ? (u & 0x7FFFFFFFu) : ~u;
    return __uint_as_float(b);
}
__device__ __forceinline__ unsigned short bf16rne(float f) {
    u32 u = __float_as_uint(f);
    u32 r = (u + 0x7FFFu + ((u >> 16) & 1u)) >> 16;
    return (unsigned short)r;
}
__device__ __forceinline__ float bflo(u32 u) { return __uint_as_float(u << 16); }
__device__ __forceinline__ float bfhi(u32 u) { return __uint_as_float(u & 0xFFFF0000u); }
// D[15:0]=bf16(lo), D[31:16]=bf16(hi)  (T12 recipe)
__device__ __forceinline__ u32 cvtpk(float lo, float hi) {
    u32 r;
    asm("v_cvt_pk_bf16_f32 %0, %1, %2" : "=v"(r) : "v"(lo), "v"(hi));
    return r;
}

// ---------- K_pq_hist: heterogeneous grid ----------
// [0, HB):            fine-bucket deg histogram (grid-stride, LDS pre-agg -> atomicAdd)
// [HB, HB+npc):       per-chunk coarse histogram g1[s*npc + c]
// [HB+npc, ...):      per-node tables Pb/Qb (bf16-packed), LDS-transposed coalesced writes
__global__ __launch_bounds__(256) void k_pq_hist(
    const float* __restrict__ x, const float* __restrict__ W1, const float* __restrict__ b1,
    const int* __restrict__ ei,
    u32* __restrict__ Pb, u32* __restrict__ Qb,
    u32* __restrict__ deg, u32* __restrict__ g1,
    int N, int E, int NB, int NSB, int npc)
{
    __shared__ u32 smem[4224];     // 16.5 KB, aliased by all roles
    int tid = threadIdx.x;
    int bid = (int)blockIdx.x;

    if (bid < HB) {
        // ---- fine-deg histogram ----
        u32* cnt = smem;           // [NB]
        for (int b = tid; b < NB; b += 256) cnt[b] = 0;
        __syncthreads();
        int nquads = E >> 2;       // host guarantees E%4==0
        const int4* d4p = (const int4*)(ei + (size_t)E);
        for (int qi = bid * 256 + tid; qi < nquads; qi += HB * 256) {
            int4 d4 = d4p[qi];
            atomicAdd(&cnt[d4.x >> NPB_SHIFT], 1u);
            atomicAdd(&cnt[d4.y >> NPB_SHIFT], 1u);
            atomicAdd(&cnt[d4.z >> NPB_SHIFT], 1u);
            atomicAdd(&cnt[d4.w >> NPB_SHIFT], 1u);
        }
        __syncthreads();
        for (int b = tid; b < NB; b += 256)
            if (cnt[b]) atomicAdd(&deg[b], cnt[b]);
        return;
    }

    if (bid < HB + npc) {
        // ---- per-chunk coarse histogram ----
        u32* cnt = smem;           // [NSB], NSB <= 64
        int c = bid - HB;
        for (int s = tid; s < NSB; s += 256) cnt[s] = 0;
        __syncthreads();
        int s0 = c * CHP, end = min(E, s0 + CHP);
        int nq = (end - s0) >> 2;
        const int4* d4p = (const int4*)(ei + (size_t)E + s0);
        for (int qi = tid; qi < nq; qi += 256) {
            int4 d4 = d4p[qi];
            atomicAdd(&cnt[d4.x >> SB_SHIFT], 1u);
            atomicAdd(&cnt[d4.y >> SB_SHIFT], 1u);
            atomicAdd(&cnt[d4.z >> SB_SHIFT], 1u);
            atomicAdd(&cnt[d4.w >> SB_SHIFT], 1u);
        }
        __syncthreads();
        for (int s = tid; s < NSB; s += 256) g1[(size_t)s * npc + c] = cnt[s];
        return;
    }

    // ---- PQ role ----
    float* sWTa = (float*)smem;            // [j][k] = W1[k][j]-W1[k+32][j]
    float* sWTb = (float*)smem + 2048;     // [j][k] = W1[k+32][j]
    for (int idx = tid; idx < 2048; idx += 256) {
        int j = idx >> 5, k = idx & 31;
        float a = W1[k * 64 + j];
        float b = W1[(k + 32) * 64 + j];
        sWTa[j * 32 + k] = a - b;
        sWTb[j * 32 + k] = b;
    }
    __syncthreads();

    int blk = bid - HB - npc;
    int n = blk * 256 + tid;

    u32 pw[32], qw[32];
    if (n < N) {
        float xr[32];
        const float4* x4 = reinterpret_cast<const float4*>(x + (size_t)n * 32);
#pragma unroll
        for (int q = 0; q < 8; ++q) {
            float4 v = x4[q];
            xr[4 * q] = v.x; xr[4 * q + 1] = v.y; xr[4 * q + 2] = v.z; xr[4 * q + 3] = v.w;
        }
        for (int j0 = 0; j0 < 64; j0 += 4) {
            float pv[4], qv[4];
#pragma unroll
            for (int m = 0; m < 4; ++m) {
                int j = j0 + m;
                float a = b1[j], q = 0.f;
#pragma unroll
                for (int k = 0; k < 32; ++k) {
                    a = fmaf(xr[k], sWTa[j * 32 + k], a);
                    q = fmaf(xr[k], sWTb[j * 32 + k], q);
                }
                pv[m] = a; qv[m] = q;
            }
            pw[(j0 >> 1)]     = (u32)bf16rne(pv[0]) | ((u32)bf16rne(pv[1]) << 16);
            pw[(j0 >> 1) + 1] = (u32)bf16rne(pv[2]) | ((u32)bf16rne(pv[3]) << 16);
            qw[(j0 >> 1)]     = (u32)bf16rne(qv[0]) | ((u32)bf16rne(qv[1]) << 16);
            qw[(j0 >> 1) + 1] = (u32)bf16rne(qv[2]) | ((u32)bf16rne(qv[3]) << 16);
        }
    }
    __syncthreads();   // weights dead; smem re-used as staging

    u32* sP = smem;            // [64][33] padded
    u32* sQ = smem + 2112;
    for (int r = 0; r < 4; ++r) {
        if ((tid >> 6) == r && n < N) {
            int row = tid & 63;
#pragma unroll
            for (int i = 0; i < 32; ++i) {
                sP[row * 33 + i] = pw[i];
                sQ[row * 33 + i] = qw[i];
            }
        }
        __syncthreads();
        int nodebase = blk * 256 + r * 64;
        size_t wbase = (size_t)nodebase * 32;
        for (int w = tid; w < 2048; w += 256) {
            int node = nodebase + (w >> 5);
            if (node < N) {
                u32 v = sP[(w >> 5) * 33 + (w & 31)];
                u32 u = sQ[(w >> 5) * 33 + (w & 31)];
                Pb[wbase + w] = v;
                Qb[wbase + w] = u;
            }
        }
        __syncthreads();
    }
}

// ---------- K_scan: single block, exclusive scan of fine deg -> base[NB+1], cursor ----------
__global__ __launch_bounds__(256) void k_scan(const u32* __restrict__ deg,
                                              u32* __restrict__ base, u32* __restrict__ cursor, int NB) {
    __shared__ u32 sh[256];
    __shared__ u32 carry;
    int t = threadIdx.x;
    if (t == 0) carry = 0;
    __syncthreads();
    for (int r0 = 0; r0 < NB; r0 += 256) {
        int i = r0 + t;
        u32 v = (i < NB) ? deg[i] : 0;
        sh[t] = v; __syncthreads();
        u32 acc = v;
        for (int off = 1; off < 256; off <<= 1) {
            u32 add = (t >= off) ? sh[t - off] : 0;
            __syncthreads();
            acc += add; sh[t] = acc;
            __syncthreads();
        }
        u32 excl = carry + acc - v;
        if (i < NB) { base[i] = excl; cursor[i] = excl; }
        __syncthreads();
        if (t == 255) carry += acc;
        __syncthreads();
    }
    if (t == 0) base[NB] = carry;
}

// ---------- generic partial scan (1024/block) + block-sum scan, for g1 ----------
__global__ __launch_bounds__(256) void k_scan1(const u32* __restrict__ deg, u32* __restrict__ cursor,
                                               u32* __restrict__ bsum, int N) {
    __shared__ u32 sh[256];
    int t = threadIdx.x;
    int base = blockIdx.x * 1024 + t * 4;
    u32 v0 = 0, v1 = 0, v2 = 0, v3 = 0;
    if (base + 3 < N) {
        uint4 vv = *reinterpret_cast<const uint4*>(deg + base);
        v0 = vv.x; v1 = vv.y; v2 = vv.z; v3 = vv.w;
    } else {
        if (base < N) v0 = deg[base];
        if (base + 1 < N) v1 = deg[base + 1];
        if (base + 2 < N) v2 = deg[base + 2];
        if (base + 3 < N) v3 = deg[base + 3];
    }
    u32 s = v0 + v1 + v2 + v3;
    sh[t] = s; __syncthreads();
    u32 acc = s;
    for (int off = 1; off < 256; off <<= 1) {
        u32 add = (t >= off) ? sh[t - off] : 0;
        __syncthreads();
        acc += add; sh[t] = acc;
        __syncthreads();
    }
    u32 excl = acc - s;
    if (base < N) cursor[base] = excl;
    if (base + 1 < N) cursor[base + 1] = excl + v0;
    if (base + 2 < N) cursor[base + 2] = excl + v0 + v1;
    if (base + 3 < N) cursor[base + 3] = excl + v0 + v1 + v2;
    if (t == 255) bsum[blockIdx.x] = acc;
}

__global__ __launch_bounds__(256) void k_scan2(const u32* __restrict__ bsum, u32* __restrict__ bsumX, int nb) {
    __shared__ u32 sh[256];
    int t = threadIdx.x;
    u32 v = (t < nb) ? bsum[t] : 0;
    sh[t] = v; __syncthreads();
    u32 acc = v;
    for (int off = 1; off < 256; off <<= 1) {
        u32 add = (t >= off) ? sh[t - off] : 0;
        __syncthreads();
        acc += add; sh[t] = acc;
        __syncthreads();
    }
    if (t < nb) bsumX[t] = acc - v;
}

// ---------- K_sp1: phase-1 scatter into coarse buckets (deterministic, coalesced runs ~84) ----------
__global__ __launch_bounds__(256) void k_sp1(const int* __restrict__ ei,
                                             const u32* __restrict__ g1cur, const u32* __restrict__ bsumX1,
                                             uint2* __restrict__ ed, int E, int NSB, int npc) {
    __shared__ u32 sb[64], cnt[64];
    int tid = threadIdx.x;
    int c = (int)blockIdx.x;
    for (int s = tid; s < NSB; s += 256) {
        size_t idx = (size_t)s * npc + c;
        sb[s] = g1cur[idx] + bsumX1[idx >> 10];
        cnt[s] = 0;
    }
    __syncthreads();
    int s0 = c * CHP, end = min(E, s0 + CHP);
    int nq = (end - s0) >> 2;
    const int4* d4p = (const int4*)(ei + (size_t)E + s0);
    const int4* s4p = (const int4*)(ei + s0);
    for (int qi = tid; qi < nq; qi += 256) {
        int4 d4 = d4p[qi];
        int4 s4 = s4p[qi];
        int dd[4] = {d4.x, d4.y, d4.z, d4.w};
        int ss[4] = {s4.x, s4.y, s4.z, s4.w};
#pragma unroll
        for (int u = 0; u < 4; ++u) {
            int s = dd[u] >> SB_SHIFT;
            u32 r = atomicAdd(&cnt[s], 1u);
            ed[sb[s] + r] = make_uint2((u32)ss[u], (u32)dd[u]);
        }
    }
}

// ---------- K_sp2: phase-2 refine into fine buckets (input coarse-sorted -> runs ~32) ----------
// payload: src (17b) | local (5b) << 17
__global__ __launch_bounds__(256) void k_sp2(const uint2* __restrict__ ed,
                                             u32* __restrict__ cursor,
                                             u32* __restrict__ sorted, int E, int NB) {
    extern __shared__ u32 sh[];    // cnt[NB], sbase[NB]
    u32* cnt   = sh;
    u32* sbase = sh + NB;
    int tid = threadIdx.x;
    for (int b = tid; b < NB; b += 256) cnt[b] = 0;
    __syncthreads();

    int s0 = (int)blockIdx.x * CHP, end = min(E, s0 + CHP);
    int n2 = (end - s0) >> 1;              // uint4 = 2 records
    const uint4* p = (const uint4*)(ed + s0);

    for (int i = tid; i < n2; i += 256) {
        uint4 v = p[i];
        atomicAdd(&cnt[v.y >> NPB_SHIFT], 1u);
        atomicAdd(&cnt[v.w >> NPB_SHIFT], 1u);
    }
    __syncthreads();

    for (int b = tid; b < NB; b += 256) {
        u32 c = cnt[b];
        if (c) { sbase[b] = atomicAdd(&cursor[b], c); cnt[b] = 0; }
    }
    __syncthreads();

    for (int i = tid; i < n2; i += 256) {
        uint4 v = p[i];
        int b1 = (int)(v.y >> NPB_SHIFT);
        u32 r1 = atomicAdd(&cnt[b1], 1u);
        sorted[sbase[b1] + r1] = v.x | ((v.y & (NPB - 1)) << 17);
        int b2 = (int)(v.w >> NPB_SHIFT);
        u32 r2 = atomicAdd(&cnt[b2], 1u);
        sorted[sbase[b2] + r2] = v.z | ((v.w & (NPB - 1)) << 17);
    }
}

// ---------- K_bucket: one block per bucket; pipelined gather + MFMA + LDS max-agg ----------
// A-frag (16x16x32 bf16): lane l holds A[row=l&15][k=(l>>4)*8 + j]
// C/D (m89-verified):     lane l, reg i -> D[row=(l>>4)*4+i][col=l&15]
__global__ __launch_bounds__(256) void k_bucket(
    const u32* __restrict__ Pb, const u32* __restrict__ Qb,
    const u32* __restrict__ sorted, const u32* __restrict__ base,
    const float* __restrict__ W2, const float* __restrict__ b2,
    float* __restrict__ out, int N, int NB)
{
    __shared__ u32 agg[NPB * 32];   // 4 KB, encoded-u32 max, 0 = "untouched"
    int b = blockIdx.x;
    int tid = threadIdx.x;
    for (int i = tid; i < NPB * 32; i += 256) agg[i] = 0u;

    int lane = tid & 63;
    int wid = tid >> 6;
    int n = lane & 15;
    int kc = lane >> 4;

    // W2 resident as 4 bf16 B-fragments
    short8v b00, b01, b10, b11;
#pragma unroll
    for (int j = 0; j < 8; ++j) {
        int k = kc * 8 + j;
        b00[j] = (short)bf16rne(W2[k * 32 + n]);
        b01[j] = (short)bf16rne(W2[(k + 32) * 32 + n]);
        b10[j] = (short)bf16rne(W2[k * 32 + n + 16]);
        b11[j] = (short)bf16rne(W2[(k + 32) * 32 + n + 16]);
    }

    u32 start = base[b];
    u32 bend  = base[b + 1];
    int ntiles = ((int)(bend - start) + 15) >> 4;
    int nodebase = b * NPB;

    __syncthreads();

    int t = wid;
    u32 slotA = start + (u32)t * 16u + (u32)n;
    u32 recA = 0;
    uint4 qA0, qA1, pA0, pA1;
    if (t < ntiles) {   // wave-uniform branch
        u32 sl = slotA < bend ? slotA : bend - 1;
        recA = sorted[sl];
        int src = (int)(recA & 0x1FFFFu);
        int loc = (int)(recA >> 17);
        const u32* qr = Qb + (size_t)src * 32;
        const u32* pr = Pb + (size_t)(nodebase + loc) * 32;
        qA0 = *(const uint4*)(qr + kc * 4);
        qA1 = *(const uint4*)(qr + 16 + kc * 4);
        pA0 = *(const uint4*)(pr + kc * 4);
        pA1 = *(const uint4*)(pr + 16 + kc * 4);
    }

    for (; t < ntiles; t += 4) {
        // ---- prefetch stage B (clamped-safe) ----
        u32 slotB = start + (u32)(t + 4) * 16u + (u32)n;
        u32 slB = slotB < bend ? slotB : bend - 1;
        u32 recB = sorted[slB];
        int srcB = (int)(recB & 0x1FFFFu);
        int locB = (int)(recB >> 17);
        const u32* qrB = Qb + (size_t)srcB * 32;
        const u32* prB = Pb + (size_t)(nodebase + locB) * 32;
        uint4 qB0 = *(const uint4*)(qrB + kc * 4);
        uint4 qB1 = *(const uint4*)(qrB + 16 + kc * 4);
        uint4 pB0 = *(const uint4*)(prB + kc * 4);
        uint4 pB1 = *(const uint4*)(prB + 16 + kc * 4);

        // ---- compute stage A ----
        bool valid = slotA < bend;
        int local = valid ? (int)(recA >> 17) : -1;

        u32 pa[4] = {pA0.x, pA0.y, pA0.z, pA0.w};
        u32 ph[4] = {pA1.x, pA1.y, pA1.z, pA1.w};
        u32 qa[4] = {qA0.x, qA0.y, qA0.z, qA0.w};
        u32 qh[4] = {qA1.x, qA1.y, qA1.z, qA1.w};

        u32x4 aw0, aw1;
#pragma unroll
        for (int u = 0; u < 4; ++u) {
            float l0 = fmaxf(bflo(pa[u]) + bflo(qa[u]), 0.f);
            float h0 = fmaxf(bfhi(pa[u]) + bfhi(qa[u]), 0.f);
            aw0[u] = cvtpk(l0, h0);
            float l1 = fmaxf(bflo(ph[u]) + bflo(qh[u]), 0.f);
            float h1 = fmaxf(bfhi(ph[u]) + bfhi(qh[u]), 0.f);
            aw1[u] = cvtpk(l1, h1);
        }
        short8v a0 = __builtin_bit_cast(short8v, aw0);
        short8v a1 = __builtin_bit_cast(short8v, aw1);

        f32x4 d0 = {0.f, 0.f, 0.f, 0.f};
        f32x4 d1 = {0.f, 0.f, 0.f, 0.f};
        d0 = __builtin_amdgcn_mfma_f32_16x16x32_bf16(a0, b00, d0, 0, 0, 0);
        d0 = __builtin_amdgcn_mfma_f32_16x16x32_bf16(a1, b01, d0, 0, 0, 0);
        d1 = __builtin_amdgcn_mfma_f32_16x16x32_bf16(a0, b10, d1, 0, 0, 0);
        d1 = __builtin_amdgcn_mfma_f32_16x16x32_bf16(a1, b11, d1, 0, 0, 0);

        // rows owned by this lane: r = kc*4 + i; row r's record lives in lane r
#pragma unroll
        for (int i = 0; i < 4; ++i) {
            int r = kc * 4 + i;
            int lr = __shfl(local, r, 64);
            if (lr >= 0) {
                int sw = (lr & 1) << 4;
                atomicMax(&agg[(lr << 5) + (n ^ sw)], enc_f32(d0[i]));
                atomicMax(&agg[(lr << 5) + ((n + 16) ^ sw)], enc_f32(d1[i]));
            }
        }

        // ---- rotate ----
        slotA = slotB; recA = recB;
        qA0 = qB0; qA1 = qB1; pA0 = pB0; pA1 = pB1;
    }

    __syncthreads();
    // fused decode + b2 + empty->0; every node written exactly once
    for (int i = tid; i < NPB * 32; i += 256) {
        int local = i >> 5, c = i & 31;
        int node = nodebase + local;
        if (node < N) {
            u32 u = agg[(local << 5) + (c ^ ((local & 1) << 4))];
            out[(size_t)node * 32 + c] = u ? (dec_f32(u) + b2[c]) : 0.f;
        }
    }
}

// ---------- fallback (round-1 style) ----------
__global__ __launch_bounds__(256) void fb_edge(const float* __restrict__ x, const int* __restrict__ ei,
                                               const float* __restrict__ W1, const float* __restrict__ b1,
                                               const float* __restrict__ W2, const float* __restrict__ b2,
                                               u32* __restrict__ out, int E) {
    int e = blockIdx.x * 256 + threadIdx.x;
    if (e >= E) return;
    int src = ei[e], dst = ei[E + e];
    float m[64];
    const float4* xi4 = reinterpret_cast<const float4*>(x + (size_t)dst * 32);
    const float4* xj4 = reinterpret_cast<const float4*>(x + (size_t)src * 32);
#pragma unroll
    for (int q = 0; q < 8; ++q) {
        float4 a = xi4[q], b = xj4[q];
        m[q * 4] = a.x; m[q * 4 + 1] = a.y; m[q * 4 + 2] = a.z; m[q * 4 + 3] = a.w;
        m[32 + q * 4] = b.x - a.x; m[32 + q * 4 + 1] = b.y - a.y;
        m[32 + q * 4 + 2] = b.z - a.z; m[32 + q * 4 + 3] = b.w - a.w;
    }
    float acc[32];
#pragma unroll
    for (int c = 0; c < 32; ++c) acc[c] = b2[c];
    for (int j = 0; j < 64; ++j) {
        float h = b1[j];
#pragma unroll
        for (int k = 0; k < 64; ++k) h = fmaf(m[k], W1[k * 64 + j], h);
        h = fmaxf(h, 0.0f);
#pragma unroll
        for (int c = 0; c < 32; ++c) acc[c] = fmaf(h, W2[j * 32 + c], acc[c]);
    }
    u32* o = out + (size_t)dst * 32;
#pragma unroll
    for (int c = 0; c < 32; ++c) atomicMax(o + c, enc_f32(acc[c]));
}
__global__ __launch_bounds__(256) void fb_decode(u32* __restrict__ buf, int n) {
    int i = blockIdx.x * 256 + threadIdx.x;
    if (i >= n) return;
    u32 u = buf[i];
    reinterpret_cast<float*>(buf)[i] = u ? dec_f32(u) : 0.f;
}

extern "C" void kernel_launch(void* const* d_in, const int* in_sizes, int n_in,
                              void* d_out, int out_size, void* d_ws, size_t ws_size,
                              hipStream_t stream) {
    const float* x  = (const float*)d_in[0];
    const int*   ei = (const int*)d_in[1];
    const float* W1 = (const float*)d_in[2];
    const float* b1 = (const float*)d_in[3];
    const float* W2 = (const float*)d_in[4];
    const float* b2 = (const float*)d_in[5];

    int N = in_sizes[0] / 32;
    int E = in_sizes[1] / 2;
    int NB  = (N + NPB - 1) / NPB;              // 3125 fine buckets
    int NSB = (N + (1 << SB_SHIFT) - 1) >> SB_SHIFT;  // 49 coarse buckets
    int npc = (E + CHP - 1) / CHP;              // 391 scatter blocks
    int M1  = NSB * npc;                        // coarse flat hist (19159)
    int nb1 = (M1 + 1023) / 1024;

    // workspace layout (256B aligned)
    char* ws = (char*)d_ws;
    size_t off = 0;
    auto alloc = [&](size_t bytes) { char* p = ws + off; off += (bytes + 255) & ~(size_t)255; return p; };
    u32*   Pb     = (u32*)alloc((size_t)N * 32 * 4);
    u32*   Qb     = (u32*)alloc((size_t)N * 32 * 4);
    u32*   deg    = (u32*)alloc((size_t)NB * 4);
    u32*   base   = (u32*)alloc((size_t)(NB + 1) * 4);
    u32*   cursor = (u32*)alloc((size_t)NB * 4);
    u32*   g1     = (u32*)alloc((size_t)M1 * 4);
    u32*   g1cur  = (u32*)alloc((size_t)M1 * 4);
    u32*   bsum1  = (u32*)alloc(256 * 4);
    u32*   bsumX1 = (u32*)alloc(256 * 4);
    uint2* ed     = (uint2*)alloc((size_t)E * 8);
    u32*   sorted = (u32*)alloc((size_t)E * 4);
    // NB<=4224 (hist LDS), NSB<=64, src fits 17b, E%4 for quad streams, M1 scan fits
    bool fits = (off <= ws_size) && (NB <= 4224) && (N < (1 << 17)) &&
                ((E & 3) == 0) && (nb1 <= 256);

    if (!fits) {
        hipMemsetAsync(d_out, 0, (size_t)out_size * 4, stream);
        int be = (E + 255) / 256;
        fb_edge<<<be, 256, 0, stream>>>(x, ei, W1, b1, W2, b2, (u32*)d_out, E);
        fb_decode<<<(out_size + 255) / 256, 256, 0, stream>>>((u32*)d_out, out_size);
        return;
    }

    hipMemsetAsync(deg, 0, (size_t)NB * 4, stream);

    int pq_blocks = (N + 255) / 256;
    k_pq_hist<<<HB + npc + pq_blocks, 256, 0, stream>>>(x, W1, b1, ei, Pb, Qb, deg, g1,
                                                        N, E, NB, NSB, npc);

    k_scan<<<1, 256, 0, stream>>>(deg, base, cursor, NB);
    k_scan1<<<nb1, 256, 0, stream>>>(g1, g1cur, bsum1, M1);
    k_scan2<<<1, 256, 0, stream>>>(bsum1, bsumX1, nb1);

    k_sp1<<<npc, 256, 0, stream>>>(ei, g1cur, bsumX1, ed, E, NSB, npc);
    k_sp2<<<npc, 256, (size_t)NB * 8, stream>>>(ed, cursor, sorted, E, NB);

    k_bucket<<<NB, 256, 0, stream>>>(Pb, Qb, sorted, base, W2, b2, (float*)d_out, N, NB);
}

// Round 10
// 137.272 us; speedup vs baseline: 15.3602x; 1.1350x over previous
//
#include <hip/hip_runtime.h>

typedef unsigned int u32;
typedef __attribute__((ext_vector_type(8))) short short8v;
typedef __attribute__((ext_vector_type(4))) u32 u32x4;
typedef __attribute__((ext_vector_type(4))) float f32x4;

#define NPB 256          // nodes per bucket (aggregation granularity)
#define NPB_SHIFT 8
#define CHP 4096         // edges per chunk (hist + scatter)

// order-preserving float<->uint encoding; enc never returns 0 for real values
__device__ __forceinline__ u32 enc_f32(float f) {
    u32 b = __float_as_uint(f);
    return (b & 0x80000000u) ? ~b : (b | 0x80000000u);
}
__device__ __forceinline__ float dec_f32(u32 u) {
    u32 b = (u & 0x80000000u) ? (u & 0x7FFFFFFFu) : ~u;
    return __uint_as_float(b);
}
__device__ __forceinline__ unsigned short bf16rne(float f) {
    u32 u = __float_as_uint(f);
    u32 r = (u + 0x7FFFu + ((u >> 16) & 1u)) >> 16;
    return (unsigned short)r;
}
__device__ __forceinline__ float bflo(u32 u) { return __uint_as_float(u << 16); }
__device__ __forceinline__ float bfhi(u32 u) { return __uint_as_float(u & 0xFFFF0000u); }
// D[15:0]=bf16(lo), D[31:16]=bf16(hi)
__device__ __forceinline__ u32 cvtpk(float lo, float hi) {
    u32 r;
    asm("v_cvt_pk_bf16_f32 %0, %1, %2" : "=v"(r) : "v"(lo), "v"(hi));
    return r;
}

// ---------- K_pq_hist: heterogeneous grid ----------
// [0, npc):      per-chunk bucket histogram g1[s*npc + c]
// [npc, ...):    per-node tables Pb/Qb (bf16-packed), LDS-transposed coalesced writes
__global__ __launch_bounds__(256) void k_pq_hist(
    const float* __restrict__ x, const float* __restrict__ W1, const float* __restrict__ b1,
    const int* __restrict__ ei,
    u32* __restrict__ Pb, u32* __restrict__ Qb, u32* __restrict__ g1,
    int N, int E, int NSB, int npc)
{
    __shared__ u32 smem[4224];     // 16.5 KB, aliased by both roles
    int tid = threadIdx.x;
    int bid = (int)blockIdx.x;

    if (bid < npc) {
        // ---- per-chunk bucket histogram ----
        u32* cnt = smem;           // [NSB] (NSB <= 512 guaranteed by host)
        int c = bid;
        for (int s = tid; s < NSB; s += 256) cnt[s] = 0;
        __syncthreads();
        int s0 = c * CHP, end = min(E, s0 + CHP);
        int nq = (end - s0) >> 2;  // host guarantees E%4==0
        const int4* d4p = (const int4*)(ei + (size_t)E + s0);
        for (int qi = tid; qi < nq; qi += 256) {
            int4 d4 = d4p[qi];
            atomicAdd(&cnt[d4.x >> NPB_SHIFT], 1u);
            atomicAdd(&cnt[d4.y >> NPB_SHIFT], 1u);
            atomicAdd(&cnt[d4.z >> NPB_SHIFT], 1u);
            atomicAdd(&cnt[d4.w >> NPB_SHIFT], 1u);
        }
        __syncthreads();
        for (int s = tid; s < NSB; s += 256) g1[(size_t)s * npc + c] = cnt[s];
        return;
    }

    // ---- PQ role ----
    float* sWTa = (float*)smem;            // [j][k] = W1[k][j]-W1[k+32][j]
    float* sWTb = (float*)smem + 2048;     // [j][k] = W1[k+32][j]
    for (int idx = tid; idx < 2048; idx += 256) {
        int j = idx >> 5, k = idx & 31;
        float a = W1[k * 64 + j];
        float b = W1[(k + 32) * 64 + j];
        sWTa[j * 32 + k] = a - b;
        sWTb[j * 32 + k] = b;
    }
    __syncthreads();

    int blk = bid - npc;
    int n = blk * 256 + tid;

    u32 pw[32], qw[32];
    if (n < N) {
        float xr[32];
        const float4* x4 = reinterpret_cast<const float4*>(x + (size_t)n * 32);
#pragma unroll
        for (int q = 0; q < 8; ++q) {
            float4 v = x4[q];
            xr[4 * q] = v.x; xr[4 * q + 1] = v.y; xr[4 * q + 2] = v.z; xr[4 * q + 3] = v.w;
        }
        for (int j0 = 0; j0 < 64; j0 += 4) {
            float pv[4], qv[4];
#pragma unroll
            for (int m = 0; m < 4; ++m) {
                int j = j0 + m;
                float a = b1[j], q = 0.f;
#pragma unroll
                for (int k = 0; k < 32; ++k) {
                    a = fmaf(xr[k], sWTa[j * 32 + k], a);
                    q = fmaf(xr[k], sWTb[j * 32 + k], q);
                }
                pv[m] = a; qv[m] = q;
            }
            pw[(j0 >> 1)]     = (u32)bf16rne(pv[0]) | ((u32)bf16rne(pv[1]) << 16);
            pw[(j0 >> 1) + 1] = (u32)bf16rne(pv[2]) | ((u32)bf16rne(pv[3]) << 16);
            qw[(j0 >> 1)]     = (u32)bf16rne(qv[0]) | ((u32)bf16rne(qv[1]) << 16);
            qw[(j0 >> 1) + 1] = (u32)bf16rne(qv[2]) | ((u32)bf16rne(qv[3]) << 16);
        }
    }
    __syncthreads();   // weights dead; smem re-used as staging

    u32* sP = smem;            // [64][33] padded
    u32* sQ = smem + 2112;
    for (int r = 0; r < 4; ++r) {
        if ((tid >> 6) == r && n < N) {
            int row = tid & 63;
#pragma unroll
            for (int i = 0; i < 32; ++i) {
                sP[row * 33 + i] = pw[i];
                sQ[row * 33 + i] = qw[i];
            }
        }
        __syncthreads();
        int nodebase = blk * 256 + r * 64;
        size_t wbase = (size_t)nodebase * 32;
        for (int w = tid; w < 2048; w += 256) {
            int node = nodebase + (w >> 5);
            if (node < N) {
                u32 v = sP[(w >> 5) * 33 + (w & 31)];
                u32 u = sQ[(w >> 5) * 33 + (w & 31)];
                Pb[wbase + w] = v;
                Qb[wbase + w] = u;
            }
        }
        __syncthreads();
    }
}

// ---------- generic partial scan (1024/block) + block-sum scan, for g1 ----------
__global__ __launch_bounds__(256) void k_scan1(const u32* __restrict__ deg, u32* __restrict__ cursor,
                                               u32* __restrict__ bsum, int N) {
    __shared__ u32 sh[256];
    int t = threadIdx.x;
    int base = blockIdx.x * 1024 + t * 4;
    u32 v0 = 0, v1 = 0, v2 = 0, v3 = 0;
    if (base + 3 < N) {
        uint4 vv = *reinterpret_cast<const uint4*>(deg + base);
        v0 = vv.x; v1 = vv.y; v2 = vv.z; v3 = vv.w;
    } else {
        if (base < N) v0 = deg[base];
        if (base + 1 < N) v1 = deg[base + 1];
        if (base + 2 < N) v2 = deg[base + 2];
        if (base + 3 < N) v3 = deg[base + 3];
    }
    u32 s = v0 + v1 + v2 + v3;
    sh[t] = s; __syncthreads();
    u32 acc = s;
    for (int off = 1; off < 256; off <<= 1) {
        u32 add = (t >= off) ? sh[t - off] : 0;
        __syncthreads();
        acc += add; sh[t] = acc;
        __syncthreads();
    }
    u32 excl = acc - s;
    if (base < N) cursor[base] = excl;
    if (base + 1 < N) cursor[base + 1] = excl + v0;
    if (base + 2 < N) cursor[base + 2] = excl + v0 + v1;
    if (base + 3 < N) cursor[base + 3] = excl + v0 + v1 + v2;
    if (t == 255) bsum[blockIdx.x] = acc;
}

__global__ __launch_bounds__(256) void k_scan2(const u32* __restrict__ bsum, u32* __restrict__ bsumX, int nb) {
    __shared__ u32 sh[256];
    int t = threadIdx.x;
    u32 v = (t < nb) ? bsum[t] : 0;
    sh[t] = v; __syncthreads();
    u32 acc = v;
    for (int off = 1; off < 256; off <<= 1) {
        u32 add = (t >= off) ? sh[t - off] : 0;
        __syncthreads();
        acc += add; sh[t] = acc;
        __syncthreads();
    }
    if (t < nb) bsumX[t] = acc - v;
}

// ---------- K_sp1: scatter u32 records into coarse buckets (deterministic bases) ----------
// record: src (17b) | local (8b) << 17
__global__ __launch_bounds__(512) void k_sp1(const int* __restrict__ ei,
                                             const u32* __restrict__ g1cur, const u32* __restrict__ bsumX1,
                                             u32* __restrict__ sorted, int E, int NSB, int npc) {
    __shared__ u32 sb[512], cnt[512];
    int tid = threadIdx.x;
    int c = (int)blockIdx.x;
    for (int s = tid; s < NSB; s += 512) {
        size_t idx = (size_t)s * npc + c;
        sb[s] = g1cur[idx] + bsumX1[idx >> 10];
        cnt[s] = 0;
    }
    __syncthreads();
    int s0 = c * CHP, end = min(E, s0 + CHP);
    int nq = (end - s0) >> 2;
    const int4* d4p = (const int4*)(ei + (size_t)E + s0);
    const int4* s4p = (const int4*)(ei + s0);
    for (int qi = tid; qi < nq; qi += 512) {
        int4 d4 = d4p[qi];
        int4 s4 = s4p[qi];
        int dd[4] = {d4.x, d4.y, d4.z, d4.w};
        int ss[4] = {s4.x, s4.y, s4.z, s4.w};
#pragma unroll
        for (int u = 0; u < 4; ++u) {
            int s = dd[u] >> NPB_SHIFT;
            u32 r = atomicAdd(&cnt[s], 1u);
            sorted[sb[s] + r] = (u32)ss[u] | ((u32)(dd[u] & (NPB - 1)) << 17);
        }
    }
}

// ---------- K_bucket: 1024 threads (16 waves) per 256-node bucket; pipelined gather + MFMA + LDS max-agg ----------
// A-frag (16x16x32 bf16): lane l holds A[row=l&15][k=(l>>4)*8 + j]
// C/D (m89-verified):     lane l, reg i -> D[row=(l>>4)*4+i][col=l&15]
__global__ __launch_bounds__(1024) void k_bucket(
    const u32* __restrict__ Pb, const u32* __restrict__ Qb,
    const u32* __restrict__ sorted, const u32* __restrict__ g1cur, const u32* __restrict__ bsumX1,
    const float* __restrict__ W2, const float* __restrict__ b2,
    float* __restrict__ out, int E, int N, int NSB, int npc)
{
    __shared__ u32 agg[NPB * 32];   // 32 KB, encoded-u32 max, 0 = "untouched"
    int b = blockIdx.x;
    int tid = threadIdx.x;
    for (int i = tid; i < NPB * 32; i += 1024) agg[i] = 0u;

    int lane = tid & 63;
    int wid = tid >> 6;            // 0..15
    int n = lane & 15;
    int kc = lane >> 4;

    // W2 resident as 4 bf16 B-fragments
    short8v b00, b01, b10, b11;
#pragma unroll
    for (int j = 0; j < 8; ++j) {
        int k = kc * 8 + j;
        b00[j] = (short)bf16rne(W2[k * 32 + n]);
        b01[j] = (short)bf16rne(W2[(k + 32) * 32 + n]);
        b10[j] = (short)bf16rne(W2[k * 32 + n + 16]);
        b11[j] = (short)bf16rne(W2[(k + 32) * 32 + n + 16]);
    }

    size_t i0 = (size_t)b * npc;
    u32 start = g1cur[i0] + bsumX1[i0 >> 10];
    u32 bend;
    if (b + 1 < NSB) {
        size_t i1 = (size_t)(b + 1) * npc;
        bend = g1cur[i1] + bsumX1[i1 >> 10];
    } else {
        bend = (u32)E;
    }
    int ntiles = ((int)(bend - start) + 15) >> 4;
    int nodebase = b << NPB_SHIFT;

    __syncthreads();

    int t = wid;
    u32 slotA = start + (u32)t * 16u + (u32)n;
    u32 recA = 0;
    uint4 qA0, qA1, pA0, pA1;
    if (t < ntiles) {   // wave-uniform branch
        u32 sl = slotA < bend ? slotA : bend - 1;
        recA = sorted[sl];
        int src = (int)(recA & 0x1FFFFu);
        int loc = (int)(recA >> 17);
        const u32* qr = Qb + (size_t)src * 32;
        const u32* pr = Pb + (size_t)(nodebase + loc) * 32;
        qA0 = *(const uint4*)(qr + kc * 4);
        qA1 = *(const uint4*)(qr + 16 + kc * 4);
        pA0 = *(const uint4*)(pr + kc * 4);
        pA1 = *(const uint4*)(pr + 16 + kc * 4);
    }

    for (; t < ntiles; t += 16) {
        // ---- prefetch next tile for this wave (clamped-safe) ----
        u32 slotB = start + (u32)(t + 16) * 16u + (u32)n;
        u32 slB = slotB < bend ? slotB : bend - 1;
        u32 recB = sorted[slB];
        int srcB = (int)(recB & 0x1FFFFu);
        int locB = (int)(recB >> 17);
        const u32* qrB = Qb + (size_t)srcB * 32;
        const u32* prB = Pb + (size_t)(nodebase + locB) * 32;
        uint4 qB0 = *(const uint4*)(qrB + kc * 4);
        uint4 qB1 = *(const uint4*)(qrB + 16 + kc * 4);
        uint4 pB0 = *(const uint4*)(prB + kc * 4);
        uint4 pB1 = *(const uint4*)(prB + 16 + kc * 4);

        // ---- compute current tile ----
        bool valid = slotA < bend;
        int local = valid ? (int)(recA >> 17) : -1;

        u32 pa[4] = {pA0.x, pA0.y, pA0.z, pA0.w};
        u32 ph[4] = {pA1.x, pA1.y, pA1.z, pA1.w};
        u32 qa[4] = {qA0.x, qA0.y, qA0.z, qA0.w};
        u32 qh[4] = {qA1.x, qA1.y, qA1.z, qA1.w};

        u32x4 aw0, aw1;
#pragma unroll
        for (int u = 0; u < 4; ++u) {
            float l0 = fmaxf(bflo(pa[u]) + bflo(qa[u]), 0.f);
            float h0 = fmaxf(bfhi(pa[u]) + bfhi(qa[u]), 0.f);
            aw0[u] = cvtpk(l0, h0);
            float l1 = fmaxf(bflo(ph[u]) + bflo(qh[u]), 0.f);
            float h1 = fmaxf(bfhi(ph[u]) + bfhi(qh[u]), 0.f);
            aw1[u] = cvtpk(l1, h1);
        }
        short8v a0 = __builtin_bit_cast(short8v, aw0);
        short8v a1 = __builtin_bit_cast(short8v, aw1);

        f32x4 d0 = {0.f, 0.f, 0.f, 0.f};
        f32x4 d1 = {0.f, 0.f, 0.f, 0.f};
        d0 = __builtin_amdgcn_mfma_f32_16x16x32_bf16(a0, b00, d0, 0, 0, 0);
        d0 = __builtin_amdgcn_mfma_f32_16x16x32_bf16(a1, b01, d0, 0, 0, 0);
        d1 = __builtin_amdgcn_mfma_f32_16x16x32_bf16(a0, b10, d1, 0, 0, 0);
        d1 = __builtin_amdgcn_mfma_f32_16x16x32_bf16(a1, b11, d1, 0, 0, 0);

        // rows owned by this lane: r = kc*4 + i; row r's record lives in lane r
#pragma unroll
        for (int i = 0; i < 4; ++i) {
            int r = kc * 4 + i;
            int lr = __shfl(local, r, 64);
            if (lr >= 0) {
                int sw = (lr & 1) << 4;
                atomicMax(&agg[(lr << 5) + (n ^ sw)], enc_f32(d0[i]));
                atomicMax(&agg[(lr << 5) + ((n + 16) ^ sw)], enc_f32(d1[i]));
            }
        }

        // ---- rotate ----
        slotA = slotB; recA = recB;
        qA0 = qB0; qA1 = qB1; pA0 = pB0; pA1 = pB1;
    }

    __syncthreads();
    // fused decode + b2 + empty->0; every node written exactly once
    for (int i = tid; i < NPB * 32; i += 1024) {
        int local = i >> 5, c = i & 31;
        int node = nodebase + local;
        if (node < N) {
            u32 u = agg[(local << 5) + (c ^ ((local & 1) << 4))];
            out[(size_t)node * 32 + c] = u ? (dec_f32(u) + b2[c]) : 0.f;
        }
    }
}

// ---------- fallback (round-1 style) ----------
__global__ __launch_bounds__(256) void fb_edge(const float* __restrict__ x, const int* __restrict__ ei,
                                               const float* __restrict__ W1, const float* __restrict__ b1,
                                               const float* __restrict__ W2, const float* __restrict__ b2,
                                               u32* __restrict__ out, int E) {
    int e = blockIdx.x * 256 + threadIdx.x;
    if (e >= E) return;
    int src = ei[e], dst = ei[E + e];
    float m[64];
    const float4* xi4 = reinterpret_cast<const float4*>(x + (size_t)dst * 32);
    const float4* xj4 = reinterpret_cast<const float4*>(x + (size_t)src * 32);
#pragma unroll
    for (int q = 0; q < 8; ++q) {
        float4 a = xi4[q], b = xj4[q];
        m[q * 4] = a.x; m[q * 4 + 1] = a.y; m[q * 4 + 2] = a.z; m[q * 4 + 3] = a.w;
        m[32 + q * 4] = b.x - a.x; m[32 + q * 4 + 1] = b.y - a.y;
        m[32 + q * 4 + 2] = b.z - a.z; m[32 + q * 4 + 3] = b.w - a.w;
    }
    float acc[32];
#pragma unroll
    for (int c = 0; c < 32; ++c) acc[c] = b2[c];
    for (int j = 0; j < 64; ++j) {
        float h = b1[j];
#pragma unroll
        for (int k = 0; k < 64; ++k) h = fmaf(m[k], W1[k * 64 + j], h);
        h = fmaxf(h, 0.0f);
#pragma unroll
        for (int c = 0; c < 32; ++c) acc[c] = fmaf(h, W2[j * 32 + c], acc[c]);
    }
    u32* o = out + (size_t)dst * 32;
#pragma unroll
    for (int c = 0; c < 32; ++c) atomicMax(o + c, enc_f32(acc[c]));
}
__global__ __launch_bounds__(256) void fb_decode(u32* __restrict__ buf, int n) {
    int i = blockIdx.x * 256 + threadIdx.x;
    if (i >= n) return;
    u32 u = buf[i];
    reinterpret_cast<float*>(buf)[i] = u ? dec_f32(u) : 0.f;
}

extern "C" void kernel_launch(void* const* d_in, const int* in_sizes, int n_in,
                              void* d_out, int out_size, void* d_ws, size_t ws_size,
                              hipStream_t stream) {
    const float* x  = (const float*)d_in[0];
    const int*   ei = (const int*)d_in[1];
    const float* W1 = (const float*)d_in[2];
    const float* b1 = (const float*)d_in[3];
    const float* W2 = (const float*)d_in[4];
    const float* b2 = (const float*)d_in[5];

    int N = in_sizes[0] / 32;
    int E = in_sizes[1] / 2;
    int NSB = (N + NPB - 1) >> NPB_SHIFT;       // 391 buckets of 256 nodes
    int npc = (E + CHP - 1) / CHP;              // 391 chunks
    int M1  = NSB * npc;                        // flat hist (152881)
    int nb1 = (M1 + 1023) / 1024;

    // workspace layout (256B aligned)
    char* ws = (char*)d_ws;
    size_t off = 0;
    auto alloc = [&](size_t bytes) { char* p = ws + off; off += (bytes + 255) & ~(size_t)255; return p; };
    u32*   Pb     = (u32*)alloc((size_t)N * 32 * 4);
    u32*   Qb     = (u32*)alloc((size_t)N * 32 * 4);
    u32*   g1     = (u32*)alloc((size_t)M1 * 4);
    u32*   g1cur  = (u32*)alloc((size_t)M1 * 4);
    u32*   bsum1  = (u32*)alloc(256 * 4);
    u32*   bsumX1 = (u32*)alloc(256 * 4);
    u32*   sorted = (u32*)alloc((size_t)E * 4);
    // NSB<=512 (sp1 LDS arrays), src fits 17b, E%4 for quad streams, M1 scan fits
    bool fits = (off <= ws_size) && (NSB <= 512) && (N < (1 << 17)) &&
                ((E & 3) == 0) && (nb1 <= 256);

    if (!fits) {
        hipMemsetAsync(d_out, 0, (size_t)out_size * 4, stream);
        int be = (E + 255) / 256;
        fb_edge<<<be, 256, 0, stream>>>(x, ei, W1, b1, W2, b2, (u32*)d_out, E);
        fb_decode<<<(out_size + 255) / 256, 256, 0, stream>>>((u32*)d_out, out_size);
        return;
    }

    int pq_blocks = (N + 255) / 256;
    k_pq_hist<<<npc + pq_blocks, 256, 0, stream>>>(x, W1, b1, ei, Pb, Qb, g1, N, E, NSB, npc);

    k_scan1<<<nb1, 256, 0, stream>>>(g1, g1cur, bsum1, M1);
    k_scan2<<<1, 256, 0, stream>>>(bsum1, bsumX1, nb1);

    k_sp1<<<npc, 512, 0, stream>>>(ei, g1cur, bsumX1, sorted, E, NSB, npc);

    k_bucket<<<NSB, 1024, 0, stream>>>(Pb, Qb, sorted, g1cur, bsumX1, W2, b2, (float*)d_out, E, N, NSB, npc);
}